// Round 3
// baseline (7062.847 us; speedup 1.0000x reference)
//
#include <hip/hip_runtime.h>
#include <hip/hip_bf16.h>
#include <math.h>

// Fused CBAM + deformable-conv pipeline, fp32 compute, FP32 OUTPUT.
// om1 (510 MB) is never materialized: consumed per-pixel inside dsta_dcn.
// ws layout (f32): x2 | x2s | x2f | x3 | stats | ap | mp | sig | om2
// om2 staged f32 (181 MiB total) or bf16 (120.4 MiB) if ws_size is short.

constexpr int B = 4, N = 64, F = 32;
constexpr int H = 192, W = 192, HW = H * W;
constexpr int H2 = 96, W2 = 96, HW2 = H2 * W2;
constexpr int OMC = 864;  // f*27 output channels of mask1/mask2

__device__ __forceinline__ float sigmoidf_(float v) {
  return 1.f / (1.f + expf(-v));
}
__device__ __forceinline__ float ld_(const float* p) { return *p; }
__device__ __forceinline__ float ld_(const __hip_bfloat16* p) {
  return __bfloat162float(*p);
}
__device__ __forceinline__ void st_(float* p, float v) { *p = v; }
__device__ __forceinline__ void st_(__hip_bfloat16* p, float v) {
  *p = __float2bfloat16(v);
}

// ---- diagnostic fill (sentinel values decodable from reported absmax) ----
__global__ __launch_bounds__(256) void dsta_fill(float* __restrict__ out,
                                                 int n, float v) {
  int i = blockIdx.x * 256 + threadIdx.x;
  if (i < n) out[i] = v;
}

// ---- conv1: x(B,64,H,W) -> x2(B,32,H,W), 3x3 pad1, bias, relu ----
__global__ __launch_bounds__(256) void dsta_conv1(
    const float* __restrict__ x, const float* __restrict__ wgt,
    const float* __restrict__ bias, float* __restrict__ x2) {
  int idx = blockIdx.x * 256 + threadIdx.x;   // B*4*HW
  int p = idx % HW; int r = idx / HW;
  int g = r % 4, b = r / 4;
  int h = p / W, w = p % W;
  float acc[8];
#pragma unroll
  for (int j = 0; j < 8; ++j) acc[j] = bias[g * 8 + j];
  for (int ci = 0; ci < N; ++ci) {
    const float* xp = x + ((size_t)(b * N + ci)) * HW;
    float tap[9];
#pragma unroll
    for (int t = 0; t < 9; ++t) {
      int yy = h + t / 3 - 1, xx = w + t % 3 - 1;
      tap[t] = (yy >= 0 && yy < H && xx >= 0 && xx < W) ? xp[yy * W + xx] : 0.f;
    }
#pragma unroll
    for (int j = 0; j < 8; ++j) {
      const float* wp = wgt + ((size_t)(g * 8 + j) * N + ci) * 9;
#pragma unroll
      for (int t = 0; t < 9; ++t) acc[j] = fmaf(wp[t], tap[t], acc[j]);
    }
  }
#pragma unroll
  for (int j = 0; j < 8; ++j)
    x2[((size_t)(b * F + g * 8 + j)) * HW + p] = fmaxf(acc[j], 0.f);
}

// ---- channel mean & max maps -> stats(B,2,H,W) ----
__global__ __launch_bounds__(256) void dsta_stats(
    const float* __restrict__ x2, float* __restrict__ stats) {
  int idx = blockIdx.x * 256 + threadIdx.x;   // B*HW
  int p = idx % HW, b = idx / HW;
  float s = 0.f, m = -3.4e38f;
  for (int c = 0; c < F; ++c) {
    float v = x2[((size_t)(b * F + c)) * HW + p];
    s += v; m = fmaxf(m, v);
  }
  stats[((size_t)(b * 2 + 0)) * HW + p] = s * (1.f / F);
  stats[((size_t)(b * 2 + 1)) * HW + p] = m;
}

// ---- per-(b,c) spatial mean & max -> ap, mp ----
__global__ __launch_bounds__(256) void dsta_ca_red(
    const float* __restrict__ x2, float* __restrict__ ap, float* __restrict__ mp) {
  __shared__ float ss[256], sm[256];
  int bc = blockIdx.x;  // 0..B*F-1
  const float* src = x2 + (size_t)bc * HW;
  float s = 0.f, m = -3.4e38f;
  for (int i = threadIdx.x; i < HW; i += 256) {
    float v = src[i]; s += v; m = fmaxf(m, v);
  }
  ss[threadIdx.x] = s; sm[threadIdx.x] = m;
  __syncthreads();
  for (int o = 128; o > 0; o >>= 1) {
    if (threadIdx.x < o) {
      ss[threadIdx.x] += ss[threadIdx.x + o];
      sm[threadIdx.x] = fmaxf(sm[threadIdx.x], sm[threadIdx.x + o]);
    }
    __syncthreads();
  }
  if (threadIdx.x == 0) { ap[bc] = ss[0] * (1.f / HW); mp[bc] = sm[0]; }
}

// ---- channel-attention MLP ----
__global__ __launch_bounds__(128) void dsta_ca_mlp(
    const float* __restrict__ ap, const float* __restrict__ mp,
    const float* __restrict__ w1, const float* __restrict__ w2,
    float* __restrict__ sig) {
  int t = threadIdx.x;
  if (t >= B * F) return;
  int b = t / F, co = t % F;
  float accA = 0.f, accB = 0.f;
  for (int j = 0; j < F / 2; ++j) {
    float hA = 0.f, hB = 0.f;
    for (int c = 0; c < F; ++c) {
      float wv = w1[j * F + c];
      hA = fmaf(wv, ap[b * F + c], hA);
      hB = fmaf(wv, mp[b * F + c], hB);
    }
    hA = fmaxf(hA, 0.f); hB = fmaxf(hB, 0.f);
    float wv2 = w2[co * (F / 2) + j];
    accA = fmaf(wv2, hA, accA);
    accB = fmaf(wv2, hB, accB);
  }
  sig[t] = sigmoidf_(accA + accB);
}

// ---- spatial attention: 7x7 conv(pad3) over stats, then silu ----
__global__ __launch_bounds__(256) void dsta_sa(
    const float* __restrict__ stats, const float* __restrict__ wgt,
    float* __restrict__ x2s) {
  int idx = blockIdx.x * 256 + threadIdx.x;   // B*4*HW
  int p = idx % HW; int r = idx / HW;
  int g = r % 4, b = r / 4;
  int h = p / W, w = p % W;
  float acc[8];
#pragma unroll
  for (int j = 0; j < 8; ++j) acc[j] = 0.f;   // no bias
  for (int ci = 0; ci < 2; ++ci) {
    const float* sp = stats + ((size_t)(b * 2 + ci)) * HW;
    for (int ky = 0; ky < 7; ++ky) {
      int yy = h + ky - 3;
      float tap[7];
#pragma unroll
      for (int kx = 0; kx < 7; ++kx) {
        int xx = w + kx - 3;
        tap[kx] = (yy >= 0 && yy < H && xx >= 0 && xx < W) ? sp[yy * W + xx] : 0.f;
      }
#pragma unroll
      for (int j = 0; j < 8; ++j) {
        const float* wp = wgt + (((size_t)(g * 8 + j) * 2 + ci) * 49) + ky * 7;
#pragma unroll
        for (int kx = 0; kx < 7; ++kx) acc[j] = fmaf(wp[kx], tap[kx], acc[j]);
      }
    }
  }
#pragma unroll
  for (int j = 0; j < 8; ++j) {
    float v = acc[j];
    x2s[((size_t)(b * F + g * 8 + j)) * HW + p] = sigmoidf_(v) * v;
  }
}

// ---- fuse: x2f = relu( fuse_w * [x2s ; sig*x2] + fuse_b ) ----
__global__ __launch_bounds__(256) void dsta_fuse(
    const float* __restrict__ x2s, const float* __restrict__ x2,
    const float* __restrict__ sig, const float* __restrict__ fw,
    const float* __restrict__ fb, float* __restrict__ x2f) {
  int idx = blockIdx.x * 256 + threadIdx.x;   // B*HW
  int p = idx % HW, b = idx / HW;
  float acc[F];
#pragma unroll
  for (int o = 0; o < F; ++o) acc[o] = fb[o];
  for (int c = 0; c < F; ++c) {
    float v = x2s[((size_t)(b * F + c)) * HW + p];
#pragma unroll
    for (int o = 0; o < F; ++o) acc[o] = fmaf(fw[o * 2 * F + c], v, acc[o]);
  }
  for (int c = 0; c < F; ++c) {
    float v = sig[b * F + c] * x2[((size_t)(b * F + c)) * HW + p];
#pragma unroll
    for (int o = 0; o < F; ++o) acc[o] = fmaf(fw[o * 2 * F + F + c], v, acc[o]);
  }
#pragma unroll
  for (int o = 0; o < F; ++o)
    x2f[((size_t)(b * F + o)) * HW + p] = fmaxf(acc[o], 0.f);
}

// ---- down: 3x3 stride2 pad1 conv 32->32 + relu, out 96x96 ----
__global__ __launch_bounds__(256) void dsta_down(
    const float* __restrict__ x2f, const float* __restrict__ wgt,
    const float* __restrict__ bias, float* __restrict__ x3) {
  int idx = blockIdx.x * 256 + threadIdx.x;   // B*4*HW2
  int p = idx % HW2; int r = idx / HW2;
  int g = r % 4, b = r / 4;
  int h2 = p / W2, w2 = p % W2;
  float acc[8];
#pragma unroll
  for (int j = 0; j < 8; ++j) acc[j] = bias[g * 8 + j];
  for (int ci = 0; ci < F; ++ci) {
    const float* xp = x2f + ((size_t)(b * F + ci)) * HW;
    float tap[9];
#pragma unroll
    for (int t = 0; t < 9; ++t) {
      int yy = 2 * h2 + t / 3 - 1, xx = 2 * w2 + t % 3 - 1;
      tap[t] = (yy >= 0 && yy < H && xx >= 0 && xx < W) ? xp[yy * W + xx] : 0.f;
    }
#pragma unroll
    for (int j = 0; j < 8; ++j) {
      const float* wp = wgt + ((size_t)(g * 8 + j) * F + ci) * 9;
#pragma unroll
      for (int t = 0; t < 9; ++t) acc[j] = fmaf(wp[t], tap[t], acc[j]);
    }
  }
#pragma unroll
  for (int j = 0; j < 8; ++j)
    x3[((size_t)(b * F + g * 8 + j)) * HW2 + p] = fmaxf(acc[j], 0.f);
}

// ---- om2: 3x3 pad1 conv 32->864 over x3 (96x96), + bias ----
template <typename T>
__global__ __launch_bounds__(256) void dsta_om2(
    const float* __restrict__ x3, const float* __restrict__ wgt,
    const float* __restrict__ bias, T* __restrict__ om2) {
  int idx = blockIdx.x * 256 + threadIdx.x;   // B*108*HW2
  int p = idx % HW2; int r = idx / HW2;
  int g = r % 108, b = r / 108;
  int h2 = p / W2, w2 = p % W2;
  float acc[8];
#pragma unroll
  for (int j = 0; j < 8; ++j) acc[j] = bias[g * 8 + j];
  for (int ci = 0; ci < F; ++ci) {
    const float* xp = x3 + ((size_t)(b * F + ci)) * HW2;
    float tap[9];
#pragma unroll
    for (int t = 0; t < 9; ++t) {
      int yy = h2 + t / 3 - 1, xx = w2 + t % 3 - 1;
      tap[t] = (yy >= 0 && yy < H2 && xx >= 0 && xx < W2) ? xp[yy * W2 + xx] : 0.f;
    }
#pragma unroll
    for (int j = 0; j < 8; ++j) {
      const float* wp = wgt + ((size_t)(g * 8 + j) * F + ci) * 9;
#pragma unroll
      for (int t = 0; t < 9; ++t) acc[j] = fmaf(wp[t], tap[t], acc[j]);
    }
  }
#pragma unroll
  for (int j = 0; j < 8; ++j)
    st_(&om2[((size_t)(b * OMC + g * 8 + j)) * HW2 + p], acc[j]);
}

// ---- fused: per-pixel om1 conv + bilinear om2 + DCNv2 + relu ----
template <typename T>
__global__ __launch_bounds__(256) void dsta_dcn(
    const float* __restrict__ x2f, const T* __restrict__ om2,
    const float* __restrict__ mw, const float* __restrict__ mb,
    const float* __restrict__ dw, const float* __restrict__ db,
    float* __restrict__ dcn) {
  int idx = blockIdx.x * 256 + threadIdx.x;   // B*HW
  int p = idx % HW, b = idx / HW;
  int h = p / W, w = p % W;

  // jax bilinear 96->192: src = dst*0.5 - 0.25; border renorm == clamp here
  float sy = h * 0.5f - 0.25f;
  float sx = w * 0.5f - 0.25f;
  float fy0 = floorf(sy), fx0 = floorf(sx);
  float gy = sy - fy0, gx = sx - fx0;
  int y0 = (int)fy0, x0 = (int)fx0;
  int y0c = min(max(y0, 0), H2 - 1), y1c = min(max(y0 + 1, 0), H2 - 1);
  int x0c = min(max(x0, 0), W2 - 1), x1c = min(max(x0 + 1, 0), W2 - 1);
  float b00 = (1.f - gy) * (1.f - gx), b01 = (1.f - gy) * gx;
  float b10 = gy * (1.f - gx), b11 = gy * gx;
  int i00 = y0c * W2 + x0c, i01 = y0c * W2 + x1c;
  int i10 = y1c * W2 + x0c, i11 = y1c * W2 + x1c;

  const T* om2b = om2 + (size_t)b * OMC * HW2;
  const float* xb = x2f + (size_t)b * F * HW;

  float acc[F];
#pragma unroll
  for (int o = 0; o < F; ++o) acc[o] = db[o];

  for (int c = 0; c < F; ++c) {
    // om channels for this c: 18 offset ch (c*18..), 9 mask ch (576+9c..)
    float om[27];
#pragma unroll
    for (int j = 0; j < 27; ++j) {
      int ch = (j < 18) ? (c * 18 + j) : (576 + c * 9 + (j - 18));
      const T* pl = om2b + (size_t)ch * HW2;
      om[j] = mb[ch] + b00 * ld_(pl + i00) + b01 * ld_(pl + i01) +
              b10 * ld_(pl + i10) + b11 * ld_(pl + i11);
    }
    // om1 = 3x3 pad1 conv of x2f at this pixel (27 outputs for this c)
    for (int ci = 0; ci < F; ++ci) {
      const float* xp = xb + (size_t)ci * HW;
      float tap[9];
#pragma unroll
      for (int t = 0; t < 9; ++t) {
        int yy = h + t / 3 - 1, xx = w + t % 3 - 1;
        tap[t] = (yy >= 0 && yy < H && xx >= 0 && xx < W) ? xp[yy * W + xx] : 0.f;
      }
#pragma unroll
      for (int j = 0; j < 27; ++j) {
        int ch = (j < 18) ? (c * 18 + j) : (576 + c * 9 + (j - 18));
        const float* wp = mw + ((size_t)ch * F + ci) * 9;
#pragma unroll
        for (int t = 0; t < 9; ++t) om[j] = fmaf(wp[t], tap[t], om[j]);
      }
    }
    // deformable sampling of x2f channel c at 9 offset taps
    const float* xc = xb + (size_t)c * HW;
#pragma unroll
    for (int k = 0; k < 9; ++k) {
      float m = sigmoidf_(om[18 + k]);
      float py = (float)(h + k / 3 - 1) + om[2 * k];
      float px = (float)(w + k % 3 - 1) + om[2 * k + 1];
      float fpy = floorf(py), fpx = floorf(px);
      int yi = (int)fpy, xi = (int)fpx;
      float wy = py - fpy, wx = px - fpx;
      float v00 = (yi >= 0 && yi < H && xi >= 0 && xi < W) ? xc[yi * W + xi] : 0.f;
      float v01 = (yi >= 0 && yi < H && xi + 1 >= 0 && xi + 1 < W) ? xc[yi * W + xi + 1] : 0.f;
      float v10 = (yi + 1 >= 0 && yi + 1 < H && xi >= 0 && xi < W) ? xc[(yi + 1) * W + xi] : 0.f;
      float v11 = (yi + 1 >= 0 && yi + 1 < H && xi + 1 >= 0 && xi + 1 < W) ? xc[(yi + 1) * W + xi + 1] : 0.f;
      float val = (v00 * (1.f - wy) * (1.f - wx) + v01 * (1.f - wy) * wx +
                   v10 * wy * (1.f - wx) + v11 * wy * wx) * m;
#pragma unroll
      for (int o = 0; o < F; ++o)
        acc[o] = fmaf(val, dw[(o * F + c) * 9 + k], acc[o]);
    }
  }
#pragma unroll
  for (int o = 0; o < F; ++o)
    dcn[((size_t)(b * F + o)) * HW + p] = fmaxf(acc[o], 0.f);
}

// ---- out: 3x3 pad1 conv 32->64 + bias + relu, FP32 output ----
__global__ __launch_bounds__(256) void dsta_out(
    const float* __restrict__ dcn, const float* __restrict__ wgt,
    const float* __restrict__ bias, float* __restrict__ out) {
  int idx = blockIdx.x * 256 + threadIdx.x;   // B*8*HW
  int p = idx % HW; int r = idx / HW;
  int g = r % 8, b = r / 8;
  int h = p / W, w = p % W;
  float acc[8];
#pragma unroll
  for (int j = 0; j < 8; ++j) acc[j] = bias[g * 8 + j];
  for (int ci = 0; ci < F; ++ci) {
    const float* xp = dcn + ((size_t)(b * F + ci)) * HW;
    float tap[9];
#pragma unroll
    for (int t = 0; t < 9; ++t) {
      int yy = h + t / 3 - 1, xx = w + t % 3 - 1;
      tap[t] = (yy >= 0 && yy < H && xx >= 0 && xx < W) ? xp[yy * W + xx] : 0.f;
    }
#pragma unroll
    for (int j = 0; j < 8; ++j) {
      const float* wp = wgt + ((size_t)(g * 8 + j) * F + ci) * 9;
#pragma unroll
      for (int t = 0; t < 9; ++t) acc[j] = fmaf(wp[t], tap[t], acc[j]);
    }
  }
#pragma unroll
  for (int j = 0; j < 8; ++j)
    out[((size_t)(b * N + g * 8 + j)) * HW + p] = fmaxf(acc[j], 0.f);
}

extern "C" void kernel_launch(void* const* d_in, const int* in_sizes, int n_in,
                              void* d_out, int out_size, void* d_ws, size_t ws_size,
                              hipStream_t stream) {
  float* out = (float*)d_out;
  const int fill_grid = (out_size + 255) / 256;

  // --- resolve input ordering (dict order expected; alphabetical fallback) ---
  // dict:  x conv1_w conv1_b sa_w ca_w1 ca_w2 fuse_w fuse_b mask1_w mask1_b
  //        down_w down_b mask2_w mask2_b dcn_w dcn_b out_w out_b
  static const int idmap[18]  = {0,1,2,3,4,5,6,7,8,9,10,11,12,13,14,15,16,17};
  static const int alphamap[18] = {17,3,2,16,0,1,9,8,11,10,7,6,13,12,5,4,15,14};
  const int* map = nullptr;
  if (n_in == 18 && in_sizes[0] == 9437184) map = idmap;
  else if (n_in == 18 && in_sizes[17] == 9437184) map = alphamap;
  if (!map) {
    dsta_fill<<<fill_grid, 256, 0, stream>>>(out, out_size, 2.0e6f);
    return;
  }
  // sanity: mask1_w must be 248832 elements under the chosen map
  if (in_sizes[map[8]] != 248832 || in_sizes[map[16]] != 18432) {
    dsta_fill<<<fill_grid, 256, 0, stream>>>(out, out_size, 3.0e6f);
    return;
  }

  const float* x       = (const float*)d_in[map[0]];
  const float* conv1_w = (const float*)d_in[map[1]];
  const float* conv1_b = (const float*)d_in[map[2]];
  const float* sa_w    = (const float*)d_in[map[3]];
  const float* ca_w1   = (const float*)d_in[map[4]];
  const float* ca_w2   = (const float*)d_in[map[5]];
  const float* fuse_w  = (const float*)d_in[map[6]];
  const float* fuse_b  = (const float*)d_in[map[7]];
  const float* mask1_w = (const float*)d_in[map[8]];
  const float* mask1_b = (const float*)d_in[map[9]];
  const float* down_w  = (const float*)d_in[map[10]];
  const float* down_b  = (const float*)d_in[map[11]];
  const float* mask2_w = (const float*)d_in[map[12]];
  const float* mask2_b = (const float*)d_in[map[13]];
  const float* dcn_w   = (const float*)d_in[map[14]];
  const float* dcn_b   = (const float*)d_in[map[15]];
  const float* out_w   = (const float*)d_in[map[16]];
  const float* out_b   = (const float*)d_in[map[17]];

  float* ws = (float*)d_ws;
  float* x2    = ws;                                 // 4,718,592 f32
  float* x2s   = x2  + (size_t)B * F * HW;           // 4,718,592 f32
  float* x2f   = x2s + (size_t)B * F * HW;           // 4,718,592 f32
  float* x3    = x2f + (size_t)B * F * HW;           // 1,179,648 f32
  float* stats = x3  + (size_t)B * F * HW2;          //   294,912 f32
  float* ap    = stats + (size_t)B * 2 * HW;
  float* mp    = ap + B * F;
  float* sig   = mp + B * F;
  float* om2f  = sig + B * F;                        // 31,850,496 elems
  float* dcn   = x2;  // alias: x2 dead after dsta_fuse

  const size_t base_f32 = 15630720;                  // floats before om2
  const size_t need_f32 = (base_f32 + 31850496ull) * 4ull;          // 181 MiB
  const size_t need_bf16 = base_f32 * 4ull + 31850496ull * 2ull;    // 120 MiB
  int om2_mode;  // 0 = f32, 1 = bf16 fallback
  if (ws_size >= need_f32) om2_mode = 0;
  else if (ws_size >= need_bf16) om2_mode = 1;
  else {
    // encode ws_size (MiB) into the sentinel: error ~= 1e6 + MiB
    dsta_fill<<<fill_grid, 256, 0, stream>>>(
        out, out_size, 1.0e6f + (float)(ws_size >> 20));
    return;
  }

  dsta_conv1<<<2304, 256, 0, stream>>>(x, conv1_w, conv1_b, x2);
  dsta_stats<<<576, 256, 0, stream>>>(x2, stats);
  dsta_ca_red<<<128, 256, 0, stream>>>(x2, ap, mp);
  dsta_ca_mlp<<<1, 128, 0, stream>>>(ap, mp, ca_w1, ca_w2, sig);
  dsta_sa<<<2304, 256, 0, stream>>>(stats, sa_w, x2s);
  dsta_fuse<<<576, 256, 0, stream>>>(x2s, x2, sig, fuse_w, fuse_b, x2f);
  dsta_down<<<576, 256, 0, stream>>>(x2f, down_w, down_b, x3);
  if (om2_mode == 0) {
    dsta_om2<float><<<15552, 256, 0, stream>>>(x3, mask2_w, mask2_b, om2f);
    dsta_dcn<float><<<576, 256, 0, stream>>>(x2f, om2f, mask1_w, mask1_b,
                                             dcn_w, dcn_b, dcn);
  } else {
    __hip_bfloat16* om2h = (__hip_bfloat16*)om2f;
    dsta_om2<__hip_bfloat16><<<15552, 256, 0, stream>>>(x3, mask2_w, mask2_b,
                                                        om2h);
    dsta_dcn<__hip_bfloat16><<<576, 256, 0, stream>>>(x2f, om2h, mask1_w,
                                                      mask1_b, dcn_w, dcn_b,
                                                      dcn);
  }
  dsta_out<<<4608, 256, 0, stream>>>(dcn, out_w, out_b, out);
}

// Round 4
// 5902.053 us; speedup vs baseline: 1.1967x; 1.1967x over previous
//
#include <hip/hip_runtime.h>
#include <hip/hip_bf16.h>
#include <math.h>

// Fused CBAM + deformable-conv pipeline, fp32 compute, FP32 OUTPUT.
// om1 (510 MB) is never materialized: consumed per-pixel inside dsta_dcn_t.
// R4: LDS-tiled dcn + om2 (the two giants). 8x8 pixel tiles, zero-padded
// 10x10x32 input patch staged in LDS; taps read from LDS instead of global.

constexpr int B = 4, N = 64, F = 32;
constexpr int H = 192, W = 192, HW = H * W;
constexpr int H2 = 96, W2 = 96, HW2 = H2 * W2;
constexpr int OMC = 864;  // f*27 output channels of mask1/mask2

__device__ __forceinline__ float sigmoidf_(float v) {
  return 1.f / (1.f + expf(-v));
}
__device__ __forceinline__ float ld_(const float* p) { return *p; }
__device__ __forceinline__ float ld_(const __hip_bfloat16* p) {
  return __bfloat162float(*p);
}
__device__ __forceinline__ void st_(float* p, float v) { *p = v; }
__device__ __forceinline__ void st_(__hip_bfloat16* p, float v) {
  *p = __float2bfloat16(v);
}

// ---- diagnostic fill ----
__global__ __launch_bounds__(256) void dsta_fill(float* __restrict__ out,
                                                 int n, float v) {
  int i = blockIdx.x * 256 + threadIdx.x;
  if (i < n) out[i] = v;
}

// ---- conv1: x(B,64,H,W) -> x2(B,32,H,W), 3x3 pad1, bias, relu ----
__global__ __launch_bounds__(256) void dsta_conv1(
    const float* __restrict__ x, const float* __restrict__ wgt,
    const float* __restrict__ bias, float* __restrict__ x2) {
  int idx = blockIdx.x * 256 + threadIdx.x;   // B*4*HW
  int p = idx % HW; int r = idx / HW;
  int g = r % 4, b = r / 4;
  int h = p / W, w = p % W;
  float acc[8];
#pragma unroll
  for (int j = 0; j < 8; ++j) acc[j] = bias[g * 8 + j];
  for (int ci = 0; ci < N; ++ci) {
    const float* xp = x + ((size_t)(b * N + ci)) * HW;
    float tap[9];
#pragma unroll
    for (int t = 0; t < 9; ++t) {
      int yy = h + t / 3 - 1, xx = w + t % 3 - 1;
      tap[t] = (yy >= 0 && yy < H && xx >= 0 && xx < W) ? xp[yy * W + xx] : 0.f;
    }
#pragma unroll
    for (int j = 0; j < 8; ++j) {
      const float* wp = wgt + ((size_t)(g * 8 + j) * N + ci) * 9;
#pragma unroll
      for (int t = 0; t < 9; ++t) acc[j] = fmaf(wp[t], tap[t], acc[j]);
    }
  }
#pragma unroll
  for (int j = 0; j < 8; ++j)
    x2[((size_t)(b * F + g * 8 + j)) * HW + p] = fmaxf(acc[j], 0.f);
}

// ---- channel mean & max maps -> stats(B,2,H,W) ----
__global__ __launch_bounds__(256) void dsta_stats(
    const float* __restrict__ x2, float* __restrict__ stats) {
  int idx = blockIdx.x * 256 + threadIdx.x;   // B*HW
  int p = idx % HW, b = idx / HW;
  float s = 0.f, m = -3.4e38f;
  for (int c = 0; c < F; ++c) {
    float v = x2[((size_t)(b * F + c)) * HW + p];
    s += v; m = fmaxf(m, v);
  }
  stats[((size_t)(b * 2 + 0)) * HW + p] = s * (1.f / F);
  stats[((size_t)(b * 2 + 1)) * HW + p] = m;
}

// ---- per-(b,c) spatial mean & max -> ap, mp ----
__global__ __launch_bounds__(256) void dsta_ca_red(
    const float* __restrict__ x2, float* __restrict__ ap, float* __restrict__ mp) {
  __shared__ float ss[256], sm[256];
  int bc = blockIdx.x;  // 0..B*F-1
  const float* src = x2 + (size_t)bc * HW;
  float s = 0.f, m = -3.4e38f;
  for (int i = threadIdx.x; i < HW; i += 256) {
    float v = src[i]; s += v; m = fmaxf(m, v);
  }
  ss[threadIdx.x] = s; sm[threadIdx.x] = m;
  __syncthreads();
  for (int o = 128; o > 0; o >>= 1) {
    if (threadIdx.x < o) {
      ss[threadIdx.x] += ss[threadIdx.x + o];
      sm[threadIdx.x] = fmaxf(sm[threadIdx.x], sm[threadIdx.x + o]);
    }
    __syncthreads();
  }
  if (threadIdx.x == 0) { ap[bc] = ss[0] * (1.f / HW); mp[bc] = sm[0]; }
}

// ---- channel-attention MLP ----
__global__ __launch_bounds__(128) void dsta_ca_mlp(
    const float* __restrict__ ap, const float* __restrict__ mp,
    const float* __restrict__ w1, const float* __restrict__ w2,
    float* __restrict__ sig) {
  int t = threadIdx.x;
  if (t >= B * F) return;
  int b = t / F, co = t % F;
  float accA = 0.f, accB = 0.f;
  for (int j = 0; j < F / 2; ++j) {
    float hA = 0.f, hB = 0.f;
    for (int c = 0; c < F; ++c) {
      float wv = w1[j * F + c];
      hA = fmaf(wv, ap[b * F + c], hA);
      hB = fmaf(wv, mp[b * F + c], hB);
    }
    hA = fmaxf(hA, 0.f); hB = fmaxf(hB, 0.f);
    float wv2 = w2[co * (F / 2) + j];
    accA = fmaf(wv2, hA, accA);
    accB = fmaf(wv2, hB, accB);
  }
  sig[t] = sigmoidf_(accA + accB);
}

// ---- spatial attention: 7x7 conv(pad3) over stats, then silu ----
__global__ __launch_bounds__(256) void dsta_sa(
    const float* __restrict__ stats, const float* __restrict__ wgt,
    float* __restrict__ x2s) {
  int idx = blockIdx.x * 256 + threadIdx.x;   // B*4*HW
  int p = idx % HW; int r = idx / HW;
  int g = r % 4, b = r / 4;
  int h = p / W, w = p % W;
  float acc[8];
#pragma unroll
  for (int j = 0; j < 8; ++j) acc[j] = 0.f;   // no bias
  for (int ci = 0; ci < 2; ++ci) {
    const float* sp = stats + ((size_t)(b * 2 + ci)) * HW;
    for (int ky = 0; ky < 7; ++ky) {
      int yy = h + ky - 3;
      float tap[7];
#pragma unroll
      for (int kx = 0; kx < 7; ++kx) {
        int xx = w + kx - 3;
        tap[kx] = (yy >= 0 && yy < H && xx >= 0 && xx < W) ? sp[yy * W + xx] : 0.f;
      }
#pragma unroll
      for (int j = 0; j < 8; ++j) {
        const float* wp = wgt + (((size_t)(g * 8 + j) * 2 + ci) * 49) + ky * 7;
#pragma unroll
        for (int kx = 0; kx < 7; ++kx) acc[j] = fmaf(wp[kx], tap[kx], acc[j]);
      }
    }
  }
#pragma unroll
  for (int j = 0; j < 8; ++j) {
    float v = acc[j];
    x2s[((size_t)(b * F + g * 8 + j)) * HW + p] = sigmoidf_(v) * v;
  }
}

// ---- fuse: x2f = relu( fuse_w * [x2s ; sig*x2] + fuse_b ) ----
__global__ __launch_bounds__(256) void dsta_fuse(
    const float* __restrict__ x2s, const float* __restrict__ x2,
    const float* __restrict__ sig, const float* __restrict__ fw,
    const float* __restrict__ fb, float* __restrict__ x2f) {
  int idx = blockIdx.x * 256 + threadIdx.x;   // B*HW
  int p = idx % HW, b = idx / HW;
  float acc[F];
#pragma unroll
  for (int o = 0; o < F; ++o) acc[o] = fb[o];
  for (int c = 0; c < F; ++c) {
    float v = x2s[((size_t)(b * F + c)) * HW + p];
#pragma unroll
    for (int o = 0; o < F; ++o) acc[o] = fmaf(fw[o * 2 * F + c], v, acc[o]);
  }
  for (int c = 0; c < F; ++c) {
    float v = sig[b * F + c] * x2[((size_t)(b * F + c)) * HW + p];
#pragma unroll
    for (int o = 0; o < F; ++o) acc[o] = fmaf(fw[o * 2 * F + F + c], v, acc[o]);
  }
#pragma unroll
  for (int o = 0; o < F; ++o)
    x2f[((size_t)(b * F + o)) * HW + p] = fmaxf(acc[o], 0.f);
}

// ---- down: 3x3 stride2 pad1 conv 32->32 + relu, out 96x96 ----
__global__ __launch_bounds__(256) void dsta_down(
    const float* __restrict__ x2f, const float* __restrict__ wgt,
    const float* __restrict__ bias, float* __restrict__ x3) {
  int idx = blockIdx.x * 256 + threadIdx.x;   // B*4*HW2
  int p = idx % HW2; int r = idx / HW2;
  int g = r % 4, b = r / 4;
  int h2 = p / W2, w2 = p % W2;
  float acc[8];
#pragma unroll
  for (int j = 0; j < 8; ++j) acc[j] = bias[g * 8 + j];
  for (int ci = 0; ci < F; ++ci) {
    const float* xp = x2f + ((size_t)(b * F + ci)) * HW;
    float tap[9];
#pragma unroll
    for (int t = 0; t < 9; ++t) {
      int yy = 2 * h2 + t / 3 - 1, xx = 2 * w2 + t % 3 - 1;
      tap[t] = (yy >= 0 && yy < H && xx >= 0 && xx < W) ? xp[yy * W + xx] : 0.f;
    }
#pragma unroll
    for (int j = 0; j < 8; ++j) {
      const float* wp = wgt + ((size_t)(g * 8 + j) * F + ci) * 9;
#pragma unroll
      for (int t = 0; t < 9; ++t) acc[j] = fmaf(wp[t], tap[t], acc[j]);
    }
  }
#pragma unroll
  for (int j = 0; j < 8; ++j)
    x3[((size_t)(b * F + g * 8 + j)) * HW2 + p] = fmaxf(acc[j], 0.f);
}

// ---- om2 (LDS-tiled): 3x3 pad1 conv 32->864 over x3 (96x96), + bias ----
// grid = B * 144 tiles * 6 chunksets; 64 threads; each block: 8x8 pixel tile,
// stages 10x10x32 zero-padded x3 patch (12.8 KB LDS), computes 144 channels.
template <typename T>
__global__ __launch_bounds__(64) void dsta_om2_t(
    const float* __restrict__ x3, const float* __restrict__ wgt,
    const float* __restrict__ bias, T* __restrict__ om2) {
  __shared__ float patch[F * 100];
  int bid = blockIdx.x;
  int cs = bid % 6;                // chunkset: 6 chunks of 24 channels
  int tile = (bid / 6) % 144;
  int b = bid / (6 * 144);
  int ty = tile / 12, tx = tile % 12;
  int y0t = ty * 8, x0t = tx * 8;
  int tid = threadIdx.x;
  // stage patch (zero-padded at image borders)
  for (int i = tid; i < F * 100; i += 64) {
    int ci = i / 100, rr = i % 100;
    int yy = y0t + rr / 10 - 1, xx = x0t + rr % 10 - 1;
    patch[i] = (yy >= 0 && yy < H2 && xx >= 0 && xx < W2)
                   ? x3[((size_t)(b * F + ci)) * HW2 + yy * W2 + xx] : 0.f;
  }
  __syncthreads();
  int py_ = tid / 8, px_ = tid % 8;
  int p2 = (y0t + py_) * W2 + (x0t + px_);
  for (int q = 0; q < 6; ++q) {
    int ch0 = (cs * 6 + q) * 24;
    float acc[24];
#pragma unroll
    for (int j = 0; j < 24; ++j) acc[j] = bias[ch0 + j];
    for (int ci = 0; ci < F; ++ci) {
      float tap[9];
      const float* pp = patch + ci * 100 + py_ * 10 + px_;
#pragma unroll
      for (int t = 0; t < 9; ++t) tap[t] = pp[(t / 3) * 10 + t % 3];
#pragma unroll
      for (int j = 0; j < 24; ++j) {
        const float* wp = wgt + ((size_t)(ch0 + j) * F + ci) * 9;
#pragma unroll
        for (int t = 0; t < 9; ++t) acc[j] = fmaf(wp[t], tap[t], acc[j]);
      }
    }
#pragma unroll
    for (int j = 0; j < 24; ++j)
      st_(&om2[((size_t)(b * OMC + ch0 + j)) * HW2 + p2], acc[j]);
  }
}

// ---- dcn (LDS-tiled): per-pixel om1 conv + bilinear om2 + DCNv2 + relu ----
// grid = B * 576 tiles; 64 threads; 8x8 pixel tile; 10x10x32 x2f patch in LDS.
template <typename T>
__global__ __launch_bounds__(64) void dsta_dcn_t(
    const float* __restrict__ x2f, const T* __restrict__ om2,
    const float* __restrict__ mw, const float* __restrict__ mb,
    const float* __restrict__ dw, const float* __restrict__ db,
    float* __restrict__ dcn) {
  __shared__ float patch[F * 100];
  int bid = blockIdx.x;
  int tile = bid % 576;
  int b = bid / 576;
  int ty = tile / 24, tx = tile % 24;
  int y0t = ty * 8, x0t = tx * 8;
  int tid = threadIdx.x;
  for (int i = tid; i < F * 100; i += 64) {
    int ci = i / 100, rr = i % 100;
    int yy = y0t + rr / 10 - 1, xx = x0t + rr % 10 - 1;
    patch[i] = (yy >= 0 && yy < H && xx >= 0 && xx < W)
                   ? x2f[((size_t)(b * F + ci)) * HW + yy * W + xx] : 0.f;
  }
  __syncthreads();
  int py_ = tid / 8, px_ = tid % 8;
  int h = y0t + py_, w = x0t + px_;
  int p = h * W + w;

  // jax bilinear 96->192: src = dst*0.5 - 0.25; border renorm == clamp here
  float sy = h * 0.5f - 0.25f;
  float sx = w * 0.5f - 0.25f;
  float fy0 = floorf(sy), fx0 = floorf(sx);
  float gy = sy - fy0, gx = sx - fx0;
  int y0 = (int)fy0, x0 = (int)fx0;
  int y0c = min(max(y0, 0), H2 - 1), y1c = min(max(y0 + 1, 0), H2 - 1);
  int x0c = min(max(x0, 0), W2 - 1), x1c = min(max(x0 + 1, 0), W2 - 1);
  float b00 = (1.f - gy) * (1.f - gx), b01 = (1.f - gy) * gx;
  float b10 = gy * (1.f - gx), b11 = gy * gx;
  int i00 = y0c * W2 + x0c, i01 = y0c * W2 + x1c;
  int i10 = y1c * W2 + x0c, i11 = y1c * W2 + x1c;

  const T* om2b = om2 + (size_t)b * OMC * HW2;
  const float* xb = x2f + (size_t)b * F * HW;

  float acc[F];
#pragma unroll
  for (int o = 0; o < F; ++o) acc[o] = db[o];

  for (int c = 0; c < F; ++c) {
    // om channels for this c: 18 offset ch (c*18..), 9 mask ch (576+9c..)
    float om[27];
#pragma unroll
    for (int j = 0; j < 27; ++j) {
      int ch = (j < 18) ? (c * 18 + j) : (576 + c * 9 + (j - 18));
      const T* pl = om2b + (size_t)ch * HW2;
      om[j] = mb[ch] + b00 * ld_(pl + i00) + b01 * ld_(pl + i01) +
              b10 * ld_(pl + i10) + b11 * ld_(pl + i11);
    }
    // om1 = 3x3 pad1 conv of x2f at this pixel, taps from LDS patch
    for (int ci = 0; ci < F; ++ci) {
      float tap[9];
      const float* pp = patch + ci * 100 + py_ * 10 + px_;
#pragma unroll
      for (int t = 0; t < 9; ++t) tap[t] = pp[(t / 3) * 10 + t % 3];
#pragma unroll
      for (int j = 0; j < 27; ++j) {
        int ch = (j < 18) ? (c * 18 + j) : (576 + c * 9 + (j - 18));
        const float* wp = mw + ((size_t)ch * F + ci) * 9;
#pragma unroll
        for (int t = 0; t < 9; ++t) om[j] = fmaf(wp[t], tap[t], om[j]);
      }
    }
    // deformable sampling of x2f channel c at 9 offset taps (global reads:
    // offsets are data-dependent and can leave the staged tile)
    const float* xc = xb + (size_t)c * HW;
#pragma unroll
    for (int k = 0; k < 9; ++k) {
      float m = sigmoidf_(om[18 + k]);
      float py = (float)(h + k / 3 - 1) + om[2 * k];
      float px = (float)(w + k % 3 - 1) + om[2 * k + 1];
      float fpy = floorf(py), fpx = floorf(px);
      int yi = (int)fpy, xi = (int)fpx;
      float wy = py - fpy, wx = px - fpx;
      float v00 = (yi >= 0 && yi < H && xi >= 0 && xi < W) ? xc[yi * W + xi] : 0.f;
      float v01 = (yi >= 0 && yi < H && xi + 1 >= 0 && xi + 1 < W) ? xc[yi * W + xi + 1] : 0.f;
      float v10 = (yi + 1 >= 0 && yi + 1 < H && xi >= 0 && xi < W) ? xc[(yi + 1) * W + xi] : 0.f;
      float v11 = (yi + 1 >= 0 && yi + 1 < H && xi + 1 >= 0 && xi + 1 < W) ? xc[(yi + 1) * W + xi + 1] : 0.f;
      float val = (v00 * (1.f - wy) * (1.f - wx) + v01 * (1.f - wy) * wx +
                   v10 * wy * (1.f - wx) + v11 * wy * wx) * m;
#pragma unroll
      for (int o = 0; o < F; ++o)
        acc[o] = fmaf(val, dw[(o * F + c) * 9 + k], acc[o]);
    }
  }
#pragma unroll
  for (int o = 0; o < F; ++o)
    dcn[((size_t)(b * F + o)) * HW + p] = fmaxf(acc[o], 0.f);
}

// ---- out: 3x3 pad1 conv 32->64 + bias + relu, FP32 output ----
__global__ __launch_bounds__(256) void dsta_out(
    const float* __restrict__ dcn, const float* __restrict__ wgt,
    const float* __restrict__ bias, float* __restrict__ out) {
  int idx = blockIdx.x * 256 + threadIdx.x;   // B*8*HW
  int p = idx % HW; int r = idx / HW;
  int g = r % 8, b = r / 8;
  int h = p / W, w = p % W;
  float acc[8];
#pragma unroll
  for (int j = 0; j < 8; ++j) acc[j] = bias[g * 8 + j];
  for (int ci = 0; ci < F; ++ci) {
    const float* xp = dcn + ((size_t)(b * F + ci)) * HW;
    float tap[9];
#pragma unroll
    for (int t = 0; t < 9; ++t) {
      int yy = h + t / 3 - 1, xx = w + t % 3 - 1;
      tap[t] = (yy >= 0 && yy < H && xx >= 0 && xx < W) ? xp[yy * W + xx] : 0.f;
    }
#pragma unroll
    for (int j = 0; j < 8; ++j) {
      const float* wp = wgt + ((size_t)(g * 8 + j) * F + ci) * 9;
#pragma unroll
      for (int t = 0; t < 9; ++t) acc[j] = fmaf(wp[t], tap[t], acc[j]);
    }
  }
#pragma unroll
  for (int j = 0; j < 8; ++j)
    out[((size_t)(b * N + g * 8 + j)) * HW + p] = fmaxf(acc[j], 0.f);
}

extern "C" void kernel_launch(void* const* d_in, const int* in_sizes, int n_in,
                              void* d_out, int out_size, void* d_ws, size_t ws_size,
                              hipStream_t stream) {
  float* out = (float*)d_out;
  const int fill_grid = (out_size + 255) / 256;

  static const int idmap[18]  = {0,1,2,3,4,5,6,7,8,9,10,11,12,13,14,15,16,17};
  static const int alphamap[18] = {17,3,2,16,0,1,9,8,11,10,7,6,13,12,5,4,15,14};
  const int* map = nullptr;
  if (n_in == 18 && in_sizes[0] == 9437184) map = idmap;
  else if (n_in == 18 && in_sizes[17] == 9437184) map = alphamap;
  if (!map) {
    dsta_fill<<<fill_grid, 256, 0, stream>>>(out, out_size, 2.0e6f);
    return;
  }
  if (in_sizes[map[8]] != 248832 || in_sizes[map[16]] != 18432) {
    dsta_fill<<<fill_grid, 256, 0, stream>>>(out, out_size, 3.0e6f);
    return;
  }

  const float* x       = (const float*)d_in[map[0]];
  const float* conv1_w = (const float*)d_in[map[1]];
  const float* conv1_b = (const float*)d_in[map[2]];
  const float* sa_w    = (const float*)d_in[map[3]];
  const float* ca_w1   = (const float*)d_in[map[4]];
  const float* ca_w2   = (const float*)d_in[map[5]];
  const float* fuse_w  = (const float*)d_in[map[6]];
  const float* fuse_b  = (const float*)d_in[map[7]];
  const float* mask1_w = (const float*)d_in[map[8]];
  const float* mask1_b = (const float*)d_in[map[9]];
  const float* down_w  = (const float*)d_in[map[10]];
  const float* down_b  = (const float*)d_in[map[11]];
  const float* mask2_w = (const float*)d_in[map[12]];
  const float* mask2_b = (const float*)d_in[map[13]];
  const float* dcn_w   = (const float*)d_in[map[14]];
  const float* dcn_b   = (const float*)d_in[map[15]];
  const float* out_w   = (const float*)d_in[map[16]];
  const float* out_b   = (const float*)d_in[map[17]];

  float* ws = (float*)d_ws;
  float* x2    = ws;                                 // 4,718,592 f32
  float* x2s   = x2  + (size_t)B * F * HW;           // 4,718,592 f32
  float* x2f   = x2s + (size_t)B * F * HW;           // 4,718,592 f32
  float* x3    = x2f + (size_t)B * F * HW;           // 1,179,648 f32
  float* stats = x3  + (size_t)B * F * HW2;          //   294,912 f32
  float* ap    = stats + (size_t)B * 2 * HW;
  float* mp    = ap + B * F;
  float* sig   = mp + B * F;
  float* om2f  = sig + B * F;                        // 31,850,496 elems
  float* dcn   = x2;  // alias: x2 dead after dsta_fuse

  const size_t base_f32 = 15630720;                  // floats before om2
  const size_t need_f32 = (base_f32 + 31850496ull) * 4ull;          // 181 MiB
  const size_t need_bf16 = base_f32 * 4ull + 31850496ull * 2ull;    // 120 MiB
  int om2_mode;  // 0 = f32, 1 = bf16 fallback
  if (ws_size >= need_f32) om2_mode = 0;
  else if (ws_size >= need_bf16) om2_mode = 1;
  else {
    dsta_fill<<<fill_grid, 256, 0, stream>>>(
        out, out_size, 1.0e6f + (float)(ws_size >> 20));
    return;
  }

  dsta_conv1<<<2304, 256, 0, stream>>>(x, conv1_w, conv1_b, x2);
  dsta_stats<<<576, 256, 0, stream>>>(x2, stats);
  dsta_ca_red<<<128, 256, 0, stream>>>(x2, ap, mp);
  dsta_ca_mlp<<<1, 128, 0, stream>>>(ap, mp, ca_w1, ca_w2, sig);
  dsta_sa<<<2304, 256, 0, stream>>>(stats, sa_w, x2s);
  dsta_fuse<<<576, 256, 0, stream>>>(x2s, x2, sig, fuse_w, fuse_b, x2f);
  dsta_down<<<576, 256, 0, stream>>>(x2f, down_w, down_b, x3);
  if (om2_mode == 0) {
    dsta_om2_t<float><<<3456, 64, 0, stream>>>(x3, mask2_w, mask2_b, om2f);
    dsta_dcn_t<float><<<2304, 64, 0, stream>>>(x2f, om2f, mask1_w, mask1_b,
                                               dcn_w, dcn_b, dcn);
  } else {
    __hip_bfloat16* om2h = (__hip_bfloat16*)om2f;
    dsta_om2_t<__hip_bfloat16><<<3456, 64, 0, stream>>>(x3, mask2_w, mask2_b,
                                                        om2h);
    dsta_dcn_t<__hip_bfloat16><<<2304, 64, 0, stream>>>(x2f, om2h, mask1_w,
                                                        mask1_b, dcn_w, dcn_b,
                                                        dcn);
  }
  dsta_out<<<4608, 256, 0, stream>>>(dcn, out_w, out_b, out);
}

// Round 5
// 4721.287 us; speedup vs baseline: 1.4960x; 1.2501x over previous
//
#include <hip/hip_runtime.h>
#include <hip/hip_bf16.h>
#include <math.h>

// Fused CBAM + deformable-conv pipeline. R5: MFMA (fp16 in, fp32 acc) for the
// two conv-GEMMs: om2 (3x3 conv 32->864 @96^2) and om1 (same @192^2, fused
// per-tile inside dcn; 510 MB om1 never materialized).
// Weight frag-packs live in d_out scratch (1.06 MB), overwritten by dsta_out.

constexpr int B = 4, N = 64, F = 32;
constexpr int H = 192, W = 192, HW = H * W;
constexpr int H2 = 96, W2 = 96, HW2 = H2 * W2;
constexpr int OMC = 864;

using u32 = unsigned int;
using f16x8 = __attribute__((ext_vector_type(8))) _Float16;
using f32x4 = __attribute__((ext_vector_type(4))) float;

__device__ __forceinline__ float sigmoidf_(float v) {
  return 1.f / (1.f + expf(-v));
}
__device__ __forceinline__ float ld2_(const float* p) { return *p; }
__device__ __forceinline__ float ld2_(const _Float16* p) { return (float)*p; }
__device__ __forceinline__ void st2_(float* p, float v) { *p = v; }
__device__ __forceinline__ void st2_(_Float16* p, float v) { *p = (_Float16)v; }
__device__ __forceinline__ f16x8 bc_(uint4 u) {
  union { uint4 u; f16x8 h; } x; x.u = u; return x.h;
}
__device__ __forceinline__ u32 pk_(float a, float b) {
  union { u32 u; _Float16 h[2]; } x; x.h[0] = (_Float16)a; x.h[1] = (_Float16)b;
  return x.u;
}

// ---- diagnostic fill ----
__global__ __launch_bounds__(256) void dsta_fill(float* __restrict__ out,
                                                 int n, float v) {
  int i = blockIdx.x * 256 + threadIdx.x;
  if (i < n) out[i] = v;
}

// ---- conv1: x(B,64,H,W) -> x2(B,32,H,W), 3x3 pad1, bias, relu ----
__global__ __launch_bounds__(256) void dsta_conv1(
    const float* __restrict__ x, const float* __restrict__ wgt,
    const float* __restrict__ bias, float* __restrict__ x2) {
  int idx = blockIdx.x * 256 + threadIdx.x;
  int p = idx % HW; int r = idx / HW;
  int g = r % 4, b = r / 4;
  int h = p / W, w = p % W;
  float acc[8];
#pragma unroll
  for (int j = 0; j < 8; ++j) acc[j] = bias[g * 8 + j];
  for (int ci = 0; ci < N; ++ci) {
    const float* xp = x + ((size_t)(b * N + ci)) * HW;
    float tap[9];
#pragma unroll
    for (int t = 0; t < 9; ++t) {
      int yy = h + t / 3 - 1, xx = w + t % 3 - 1;
      tap[t] = (yy >= 0 && yy < H && xx >= 0 && xx < W) ? xp[yy * W + xx] : 0.f;
    }
#pragma unroll
    for (int j = 0; j < 8; ++j) {
      const float* wp = wgt + ((size_t)(g * 8 + j) * N + ci) * 9;
#pragma unroll
      for (int t = 0; t < 9; ++t) acc[j] = fmaf(wp[t], tap[t], acc[j]);
    }
  }
#pragma unroll
  for (int j = 0; j < 8; ++j)
    x2[((size_t)(b * F + g * 8 + j)) * HW + p] = fmaxf(acc[j], 0.f);
}

// ---- channel mean & max maps -> stats(B,2,H,W) ----
__global__ __launch_bounds__(256) void dsta_stats(
    const float* __restrict__ x2, float* __restrict__ stats) {
  int idx = blockIdx.x * 256 + threadIdx.x;
  int p = idx % HW, b = idx / HW;
  float s = 0.f, m = -3.4e38f;
  for (int c = 0; c < F; ++c) {
    float v = x2[((size_t)(b * F + c)) * HW + p];
    s += v; m = fmaxf(m, v);
  }
  stats[((size_t)(b * 2 + 0)) * HW + p] = s * (1.f / F);
  stats[((size_t)(b * 2 + 1)) * HW + p] = m;
}

// ---- per-(b,c) spatial mean & max ----
__global__ __launch_bounds__(256) void dsta_ca_red(
    const float* __restrict__ x2, float* __restrict__ ap, float* __restrict__ mp) {
  __shared__ float ss[256], sm[256];
  int bc = blockIdx.x;
  const float* src = x2 + (size_t)bc * HW;
  float s = 0.f, m = -3.4e38f;
  for (int i = threadIdx.x; i < HW; i += 256) {
    float v = src[i]; s += v; m = fmaxf(m, v);
  }
  ss[threadIdx.x] = s; sm[threadIdx.x] = m;
  __syncthreads();
  for (int o = 128; o > 0; o >>= 1) {
    if (threadIdx.x < o) {
      ss[threadIdx.x] += ss[threadIdx.x + o];
      sm[threadIdx.x] = fmaxf(sm[threadIdx.x], sm[threadIdx.x + o]);
    }
    __syncthreads();
  }
  if (threadIdx.x == 0) { ap[bc] = ss[0] * (1.f / HW); mp[bc] = sm[0]; }
}

// ---- channel-attention MLP ----
__global__ __launch_bounds__(128) void dsta_ca_mlp(
    const float* __restrict__ ap, const float* __restrict__ mp,
    const float* __restrict__ w1, const float* __restrict__ w2,
    float* __restrict__ sig) {
  int t = threadIdx.x;
  if (t >= B * F) return;
  int b = t / F, co = t % F;
  float accA = 0.f, accB = 0.f;
  for (int j = 0; j < F / 2; ++j) {
    float hA = 0.f, hB = 0.f;
    for (int c = 0; c < F; ++c) {
      float wv = w1[j * F + c];
      hA = fmaf(wv, ap[b * F + c], hA);
      hB = fmaf(wv, mp[b * F + c], hB);
    }
    hA = fmaxf(hA, 0.f); hB = fmaxf(hB, 0.f);
    float wv2 = w2[co * (F / 2) + j];
    accA = fmaf(wv2, hA, accA);
    accB = fmaf(wv2, hB, accB);
  }
  sig[t] = sigmoidf_(accA + accB);
}

// ---- spatial attention: 7x7 conv(pad3), silu ----
__global__ __launch_bounds__(256) void dsta_sa(
    const float* __restrict__ stats, const float* __restrict__ wgt,
    float* __restrict__ x2s) {
  int idx = blockIdx.x * 256 + threadIdx.x;
  int p = idx % HW; int r = idx / HW;
  int g = r % 4, b = r / 4;
  int h = p / W, w = p % W;
  float acc[8];
#pragma unroll
  for (int j = 0; j < 8; ++j) acc[j] = 0.f;
  for (int ci = 0; ci < 2; ++ci) {
    const float* sp = stats + ((size_t)(b * 2 + ci)) * HW;
    for (int ky = 0; ky < 7; ++ky) {
      int yy = h + ky - 3;
      float tap[7];
#pragma unroll
      for (int kx = 0; kx < 7; ++kx) {
        int xx = w + kx - 3;
        tap[kx] = (yy >= 0 && yy < H && xx >= 0 && xx < W) ? sp[yy * W + xx] : 0.f;
      }
#pragma unroll
      for (int j = 0; j < 8; ++j) {
        const float* wp = wgt + (((size_t)(g * 8 + j) * 2 + ci) * 49) + ky * 7;
#pragma unroll
        for (int kx = 0; kx < 7; ++kx) acc[j] = fmaf(wp[kx], tap[kx], acc[j]);
      }
    }
  }
#pragma unroll
  for (int j = 0; j < 8; ++j) {
    float v = acc[j];
    x2s[((size_t)(b * F + g * 8 + j)) * HW + p] = sigmoidf_(v) * v;
  }
}

// ---- fuse ----
__global__ __launch_bounds__(256) void dsta_fuse(
    const float* __restrict__ x2s, const float* __restrict__ x2,
    const float* __restrict__ sig, const float* __restrict__ fw,
    const float* __restrict__ fb, float* __restrict__ x2f) {
  int idx = blockIdx.x * 256 + threadIdx.x;
  int p = idx % HW, b = idx / HW;
  float acc[F];
#pragma unroll
  for (int o = 0; o < F; ++o) acc[o] = fb[o];
  for (int c = 0; c < F; ++c) {
    float v = x2s[((size_t)(b * F + c)) * HW + p];
#pragma unroll
    for (int o = 0; o < F; ++o) acc[o] = fmaf(fw[o * 2 * F + c], v, acc[o]);
  }
  for (int c = 0; c < F; ++c) {
    float v = sig[b * F + c] * x2[((size_t)(b * F + c)) * HW + p];
#pragma unroll
    for (int o = 0; o < F; ++o) acc[o] = fmaf(fw[o * 2 * F + F + c], v, acc[o]);
  }
#pragma unroll
  for (int o = 0; o < F; ++o)
    x2f[((size_t)(b * F + o)) * HW + p] = fmaxf(acc[o], 0.f);
}

// ---- down: 3x3 s2 p1 conv 32->32 + relu ----
__global__ __launch_bounds__(256) void dsta_down(
    const float* __restrict__ x2f, const float* __restrict__ wgt,
    const float* __restrict__ bias, float* __restrict__ x3) {
  int idx = blockIdx.x * 256 + threadIdx.x;
  int p = idx % HW2; int r = idx / HW2;
  int g = r % 4, b = r / 4;
  int h2 = p / W2, w2 = p % W2;
  float acc[8];
#pragma unroll
  for (int j = 0; j < 8; ++j) acc[j] = bias[g * 8 + j];
  for (int ci = 0; ci < F; ++ci) {
    const float* xp = x2f + ((size_t)(b * F + ci)) * HW;
    float tap[9];
#pragma unroll
    for (int t = 0; t < 9; ++t) {
      int yy = 2 * h2 + t / 3 - 1, xx = 2 * w2 + t % 3 - 1;
      tap[t] = (yy >= 0 && yy < H && xx >= 0 && xx < W) ? xp[yy * W + xx] : 0.f;
    }
#pragma unroll
    for (int j = 0; j < 8; ++j) {
      const float* wp = wgt + ((size_t)(g * 8 + j) * F + ci) * 9;
#pragma unroll
      for (int t = 0; t < 9; ++t) acc[j] = fmaf(wp[t], tap[t], acc[j]);
    }
  }
#pragma unroll
  for (int j = 0; j < 8; ++j)
    x3[((size_t)(b * F + g * 8 + j)) * HW2 + p] = fmaxf(acc[j], 0.f);
}

// ---- weight frag-pack: mask1_w -> pw1 [c][mt2][kt9][lane][r4]  (fp16 pairs)
//                        mask2_w -> pw2 [mt54][kt9][lane][r4]
// Same (lane,r,half)->k map as the im2col builder: k = kt*32 + 8*(l>>4)+2r+h.
__global__ __launch_bounds__(256) void dsta_pack(
    const float* __restrict__ mw, const float* __restrict__ m2w,
    u32* __restrict__ pw1, u32* __restrict__ pw2) {
  int i = blockIdx.x * 256 + threadIdx.x;   // 271,872 total
  if (i < 147456) {
    int r = i & 3, l = (i >> 2) & 63;
    int kt = (i >> 8) % 9, q = (i >> 8) / 9;
    int mt = q & 1, c = q >> 1;
    int ochl = mt * 16 + (l & 15);
    int k0 = kt * 32 + 8 * (l >> 4) + 2 * r;
    float v0 = 0.f, v1 = 0.f;
    if (ochl < 27) {
      int ochg = ochl < 18 ? c * 18 + ochl : 576 + c * 9 + (ochl - 18);
      v0 = mw[(size_t)ochg * 288 + k0];
      v1 = mw[(size_t)ochg * 288 + k0 + 1];
    }
    pw1[i] = pk_(v0, v1);
  } else {
    int i2 = i - 147456;                    // 124,416
    int r = i2 & 3, l = (i2 >> 2) & 63;
    int kt = (i2 >> 8) % 9, mt = (i2 >> 8) / 9;
    int och = mt * 16 + (l & 15);
    int k0 = kt * 32 + 8 * (l >> 4) + 2 * r;
    pw2[i2] = pk_(m2w[(size_t)och * 288 + k0], m2w[(size_t)och * 288 + k0 + 1]);
  }
}

// ---- cooperative im2col builder: 8x8 px tile -> fp16 frags in LDS ----
// im2 layout: [nt4][kt9][lane64][r4] u32; element (r,h): k = kt*32+8*(l>>4)+2r+h,
// col j = nt*16 + (l&15) = pixel (ly=j>>3, lx=j&7). patch: [ci][10][10] f32.
template <int SH, int SW>
__device__ __forceinline__ void build_im2col(
    const float* __restrict__ src, int y0t, int x0t,
    float* __restrict__ patch, u32* __restrict__ im2, int tid) {
  for (int i = tid; i < F * 100; i += 256) {
    int ci = i / 100, rr = i % 100;
    int yy = y0t + rr / 10 - 1, xx = x0t + rr % 10 - 1;
    patch[i] = (yy >= 0 && yy < SH && xx >= 0 && xx < SW)
                   ? src[(size_t)ci * (SH * SW) + yy * SW + xx] : 0.f;
  }
  __syncthreads();
  for (int i = tid; i < 9216; i += 256) {
    int r = i & 3, l = (i >> 2) & 63;
    int kt = (i >> 8) % 9, nt = (i >> 8) / 9;
    int j = nt * 16 + (l & 15);
    int ly = j >> 3, lx = j & 7;
    int k0 = kt * 32 + 8 * (l >> 4) + 2 * r;
    int ci0 = k0 / 9, t0 = k0 - 9 * ci0;
    int k1 = k0 + 1;
    int ci1 = k1 / 9, t1 = k1 - 9 * ci1;
    float v0 = patch[ci0 * 100 + (ly + t0 / 3) * 10 + (lx + t0 % 3)];
    float v1 = patch[ci1 * 100 + (ly + t1 / 3) * 10 + (lx + t1 % 3)];
    im2[i] = pk_(v0, v1);
  }
  __syncthreads();
}

// ---- om2 via MFMA: 3x3 p1 conv 32->864 over x3, + mask2_b ----
template <typename T>
__global__ __launch_bounds__(256) void dsta_om2_m(
    const float* __restrict__ x3, const uint4* __restrict__ pw2,
    const float* __restrict__ bias, T* __restrict__ om2) {
  __shared__ float s_patch[F * 100];
  __shared__ uint4 s_col[2304];
  int bid = blockIdx.x;                 // B*144
  int tile = bid % 144, b = bid / 144;
  int y0t = (tile / 12) * 8, x0t = (tile % 12) * 8;
  int tid = threadIdx.x;
  build_im2col<H2, W2>(x3 + (size_t)b * F * HW2, y0t, x0t, s_patch,
                       (u32*)s_col, tid);
  int w = tid >> 6, l = tid & 63;
  int lg = l >> 4, li = l & 15;
  for (int mt = w; mt < 54; mt += 4) {
    uint4 wf[9];
#pragma unroll
    for (int kt = 0; kt < 9; ++kt) wf[kt] = pw2[(mt * 9 + kt) * 64 + l];
    float b4[4];
#pragma unroll
    for (int rg = 0; rg < 4; ++rg) b4[rg] = bias[mt * 16 + lg * 4 + rg];
#pragma unroll
    for (int nt = 0; nt < 4; ++nt) {
      f32x4 acc = {0.f, 0.f, 0.f, 0.f};
#pragma unroll
      for (int kt = 0; kt < 9; ++kt)
        acc = __builtin_amdgcn_mfma_f32_16x16x32_f16(
            bc_(wf[kt]), bc_(s_col[(nt * 9 + kt) * 64 + l]), acc, 0, 0, 0);
      int j = nt * 16 + li;
      int gy = y0t + (j >> 3), gx = x0t + (j & 7);
#pragma unroll
      for (int rg = 0; rg < 4; ++rg) {
        int och = mt * 16 + lg * 4 + rg;
        st2_(&om2[((size_t)(b * OMC + och)) * HW2 + gy * W2 + gx],
             acc[rg] + b4[rg]);
      }
    }
  }
}

// ---- dcn via MFMA: per-tile om1 GEMM + bilinear om2 + DCNv2 sampling ----
// 256 thr = 4 waves; wave w owns c in [w*8, w*8+8); per-lane pixel = lane.
template <typename T>
__global__ __launch_bounds__(256, 2) void dsta_dcn_m(
    const float* __restrict__ x2f, const T* __restrict__ om2,
    const uint4* __restrict__ pw1, const float* __restrict__ mb,
    const float* __restrict__ dw, const float* __restrict__ db,
    float* __restrict__ dcn) {
  __shared__ uint4 s_col[2304];          // 36,864 B; later aliased as s_red
  __shared__ float s_om[4 * 32 * 64];    // 32,768 B; first 3200 = patch
  int bid = blockIdx.x;                  // B*576
  int tile = bid % 576, b = bid / 576;
  int y0t = (tile / 24) * 8, x0t = (tile % 24) * 8;
  int tid = threadIdx.x;
  const float* xb = x2f + (size_t)b * F * HW;
  build_im2col<H, W>(xb, y0t, x0t, s_om, (u32*)s_col, tid);

  int w = tid >> 6, l = tid & 63;
  int lg = l >> 4, li = l & 15;
  int hq = y0t + (l >> 3), wq = x0t + (l & 7);

  // bilinear setup for this lane's pixel (jax resize: src = dst*0.5 - 0.25)
  float sy = hq * 0.5f - 0.25f, sx = wq * 0.5f - 0.25f;
  float fy0 = floorf(sy), fx0 = floorf(sx);
  float gy = sy - fy0, gx = sx - fx0;
  int y0 = (int)fy0, x0 = (int)fx0;
  int y0c = min(max(y0, 0), H2 - 1), y1c = min(max(y0 + 1, 0), H2 - 1);
  int x0c = min(max(x0, 0), W2 - 1), x1c = min(max(x0 + 1, 0), W2 - 1);
  float b00 = (1.f - gy) * (1.f - gx), b01 = (1.f - gy) * gx;
  float b10 = gy * (1.f - gx), b11 = gy * gx;
  int i00 = y0c * W2 + x0c, i01 = y0c * W2 + x1c;
  int i10 = y1c * W2 + x0c, i11 = y1c * W2 + x1c;
  const T* om2b = om2 + (size_t)b * OMC * HW2;

  float accd[F];
#pragma unroll
  for (int o = 0; o < F; ++o) accd[o] = 0.f;
  float* s_omw = s_om + w * (32 * 64);

  for (int cc = 0; cc < 8; ++cc) {
    int c = w * 8 + cc;
    // (a) bilinear om2 + mask1_b (independent of MFMA -> issued early)
    float omv[27];
#pragma unroll
    for (int j = 0; j < 27; ++j) {
      int ch = (j < 18) ? (c * 18 + j) : (576 + c * 9 + (j - 18));
      const T* pl = om2b + (size_t)ch * HW2;
      omv[j] = mb[ch] + b00 * ld2_(pl + i00) + b01 * ld2_(pl + i01) +
               b10 * ld2_(pl + i10) + b11 * ld2_(pl + i11);
    }
    // (b) om1 quadrants via MFMA -> wave-private LDS slab
#pragma unroll
    for (int mt = 0; mt < 2; ++mt) {
      uint4 wf[9];
#pragma unroll
      for (int kt = 0; kt < 9; ++kt)
        wf[kt] = pw1[(((c * 2 + mt) * 9) + kt) * 64 + l];
#pragma unroll
      for (int nt = 0; nt < 4; ++nt) {
        f32x4 acc = {0.f, 0.f, 0.f, 0.f};
#pragma unroll
        for (int kt = 0; kt < 9; ++kt)
          acc = __builtin_amdgcn_mfma_f32_16x16x32_f16(
              bc_(wf[kt]), bc_(s_col[(nt * 9 + kt) * 64 + l]), acc, 0, 0, 0);
        int j = nt * 16 + li;
#pragma unroll
        for (int rg = 0; rg < 4; ++rg) {
          int ch = mt * 16 + lg * 4 + rg;
          if (ch < 27) s_omw[ch * 64 + j] = acc[rg];
        }
      }
    }
    // (c) assemble om (intra-wave LDS dep; compiler emits lgkmcnt wait)
#pragma unroll
    for (int j = 0; j < 27; ++j) omv[j] += s_omw[j * 64 + l];
    // (d) deformable sampling + dcn partial einsum
    const float* xc = xb + (size_t)c * HW;
#pragma unroll
    for (int k = 0; k < 9; ++k) {
      float m = sigmoidf_(omv[18 + k]);
      float py = (float)(hq + k / 3 - 1) + omv[2 * k];
      float px = (float)(wq + k % 3 - 1) + omv[2 * k + 1];
      float fpy = floorf(py), fpx = floorf(px);
      int yi = (int)fpy, xi = (int)fpx;
      float wy = py - fpy, wx = px - fpx;
      float v00 = (yi >= 0 && yi < H && xi >= 0 && xi < W) ? xc[yi * W + xi] : 0.f;
      float v01 = (yi >= 0 && yi < H && xi + 1 >= 0 && xi + 1 < W) ? xc[yi * W + xi + 1] : 0.f;
      float v10 = (yi + 1 >= 0 && yi + 1 < H && xi >= 0 && xi < W) ? xc[(yi + 1) * W + xi] : 0.f;
      float v11 = (yi + 1 >= 0 && yi + 1 < H && xi + 1 >= 0 && xi + 1 < W) ? xc[(yi + 1) * W + xi + 1] : 0.f;
      float val = (v00 * (1.f - wy) * (1.f - wx) + v01 * (1.f - wy) * wx +
                   v10 * wy * (1.f - wx) + v11 * wy * wx) * m;
#pragma unroll
      for (int o = 0; o < F; ++o)
        accd[o] = fmaf(val, dw[(o * F + c) * 9 + k], accd[o]);
    }
  }
  // cross-wave reduction (stride 33 -> conflict-free)
  __syncthreads();
  float* s_red = (float*)s_col;
#pragma unroll
  for (int o = 0; o < F; ++o) s_red[(w * 64 + l) * 33 + o] = accd[o];
  __syncthreads();
  int px_ = tid & 63, og = tid >> 6;
  int hp = y0t + (px_ >> 3), wp = x0t + (px_ & 7);
#pragma unroll
  for (int oo = 0; oo < 8; ++oo) {
    int o = og * 8 + oo;
    float s = db[o];
#pragma unroll
    for (int w2 = 0; w2 < 4; ++w2) s += s_red[(w2 * 64 + px_) * 33 + o];
    dcn[((size_t)(b * F + o)) * HW + hp * W + wp] = fmaxf(s, 0.f);
  }
}

// ---- out: 3x3 p1 conv 32->64 + bias + relu, FP32 output ----
__global__ __launch_bounds__(256) void dsta_out(
    const float* __restrict__ dcn, const float* __restrict__ wgt,
    const float* __restrict__ bias, float* __restrict__ out) {
  int idx = blockIdx.x * 256 + threadIdx.x;
  int p = idx % HW; int r = idx / HW;
  int g = r % 8, b = r / 8;
  int h = p / W, w = p % W;
  float acc[8];
#pragma unroll
  for (int j = 0; j < 8; ++j) acc[j] = bias[g * 8 + j];
  for (int ci = 0; ci < F; ++ci) {
    const float* xp = dcn + ((size_t)(b * F + ci)) * HW;
    float tap[9];
#pragma unroll
    for (int t = 0; t < 9; ++t) {
      int yy = h + t / 3 - 1, xx = w + t % 3 - 1;
      tap[t] = (yy >= 0 && yy < H && xx >= 0 && xx < W) ? xp[yy * W + xx] : 0.f;
    }
#pragma unroll
    for (int j = 0; j < 8; ++j) {
      const float* wp = wgt + ((size_t)(g * 8 + j) * F + ci) * 9;
#pragma unroll
      for (int t = 0; t < 9; ++t) acc[j] = fmaf(wp[t], tap[t], acc[j]);
    }
  }
#pragma unroll
  for (int j = 0; j < 8; ++j)
    out[((size_t)(b * N + g * 8 + j)) * HW + p] = fmaxf(acc[j], 0.f);
}

extern "C" void kernel_launch(void* const* d_in, const int* in_sizes, int n_in,
                              void* d_out, int out_size, void* d_ws, size_t ws_size,
                              hipStream_t stream) {
  float* out = (float*)d_out;
  const int fill_grid = (out_size + 255) / 256;

  static const int idmap[18]  = {0,1,2,3,4,5,6,7,8,9,10,11,12,13,14,15,16,17};
  static const int alphamap[18] = {17,3,2,16,0,1,9,8,11,10,7,6,13,12,5,4,15,14};
  const int* map = nullptr;
  if (n_in == 18 && in_sizes[0] == 9437184) map = idmap;
  else if (n_in == 18 && in_sizes[17] == 9437184) map = alphamap;
  if (!map) {
    dsta_fill<<<fill_grid, 256, 0, stream>>>(out, out_size, 2.0e6f);
    return;
  }
  if (in_sizes[map[8]] != 248832 || in_sizes[map[16]] != 18432) {
    dsta_fill<<<fill_grid, 256, 0, stream>>>(out, out_size, 3.0e6f);
    return;
  }

  const float* x       = (const float*)d_in[map[0]];
  const float* conv1_w = (const float*)d_in[map[1]];
  const float* conv1_b = (const float*)d_in[map[2]];
  const float* sa_w    = (const float*)d_in[map[3]];
  const float* ca_w1   = (const float*)d_in[map[4]];
  const float* ca_w2   = (const float*)d_in[map[5]];
  const float* fuse_w  = (const float*)d_in[map[6]];
  const float* fuse_b  = (const float*)d_in[map[7]];
  const float* mask1_w = (const float*)d_in[map[8]];
  const float* mask1_b = (const float*)d_in[map[9]];
  const float* down_w  = (const float*)d_in[map[10]];
  const float* down_b  = (const float*)d_in[map[11]];
  const float* mask2_w = (const float*)d_in[map[12]];
  const float* mask2_b = (const float*)d_in[map[13]];
  const float* dcn_w   = (const float*)d_in[map[14]];
  const float* dcn_b   = (const float*)d_in[map[15]];
  const float* out_w   = (const float*)d_in[map[16]];
  const float* out_b   = (const float*)d_in[map[17]];

  float* ws = (float*)d_ws;
  float* x2    = ws;                                 // 4,718,592 f32
  float* x2s   = x2  + (size_t)B * F * HW;
  float* x2f   = x2s + (size_t)B * F * HW;
  float* x3    = x2f + (size_t)B * F * HW;
  float* stats = x3  + (size_t)B * F * HW2;
  float* ap    = stats + (size_t)B * 2 * HW;
  float* mp    = ap + B * F;
  float* sig   = mp + B * F;
  float* om2f  = sig + B * F;                        // 31,850,496 elems
  float* dcn   = x2;  // alias: x2 dead after dsta_fuse

  // frag-packed weights live in d_out scratch; overwritten by dsta_out.
  u32* pw1 = (u32*)d_out;              // 147,456 u32
  u32* pw2 = pw1 + 147456;             // 124,416 u32

  const size_t base_f32 = 15630720;
  const size_t need_f32 = (base_f32 + 31850496ull) * 4ull;          // ~181 MiB
  const size_t need_f16 = base_f32 * 4ull + 31850496ull * 2ull;     // ~120 MiB
  int om2_mode;
  if (ws_size >= need_f32) om2_mode = 0;
  else if (ws_size >= need_f16) om2_mode = 1;
  else {
    dsta_fill<<<fill_grid, 256, 0, stream>>>(
        out, out_size, 1.0e6f + (float)(ws_size >> 20));
    return;
  }

  dsta_conv1<<<2304, 256, 0, stream>>>(x, conv1_w, conv1_b, x2);
  dsta_stats<<<576, 256, 0, stream>>>(x2, stats);
  dsta_ca_red<<<128, 256, 0, stream>>>(x2, ap, mp);
  dsta_ca_mlp<<<1, 128, 0, stream>>>(ap, mp, ca_w1, ca_w2, sig);
  dsta_sa<<<2304, 256, 0, stream>>>(stats, sa_w, x2s);
  dsta_fuse<<<576, 256, 0, stream>>>(x2s, x2, sig, fuse_w, fuse_b, x2f);
  dsta_down<<<576, 256, 0, stream>>>(x2f, down_w, down_b, x3);
  dsta_pack<<<1062, 256, 0, stream>>>(mask1_w, mask2_w, pw1, pw2);
  if (om2_mode == 0) {
    dsta_om2_m<float><<<576, 256, 0, stream>>>(x3, (const uint4*)pw2,
                                               mask2_b, om2f);
    dsta_dcn_m<float><<<2304, 256, 0, stream>>>(x2f, om2f, (const uint4*)pw1,
                                                mask1_b, dcn_w, dcn_b, dcn);
  } else {
    _Float16* om2h = (_Float16*)om2f;
    dsta_om2_m<_Float16><<<576, 256, 0, stream>>>(x3, (const uint4*)pw2,
                                                  mask2_b, om2h);
    dsta_dcn_m<_Float16><<<2304, 256, 0, stream>>>(x2f, om2h, (const uint4*)pw1,
                                                   mask1_b, dcn_w, dcn_b, dcn);
  }
  dsta_out<<<4608, 256, 0, stream>>>(dcn, out_w, out_b, out);
}

// Round 6
// 2629.720 us; speedup vs baseline: 2.6858x; 1.7954x over previous
//
#include <hip/hip_runtime.h>
#include <hip/hip_bf16.h>
#include <math.h>

// Fused CBAM + deformable-conv pipeline. R6: de-spill dsta_dcn_m (drop the
// __launch_bounds__(256,2) VGPR cap that forced ~4 GB of scratch traffic in
// R5), reorder per-c phases to shrink live state, split om2 grid 2x.

constexpr int B = 4, N = 64, F = 32;
constexpr int H = 192, W = 192, HW = H * W;
constexpr int H2 = 96, W2 = 96, HW2 = H2 * W2;
constexpr int OMC = 864;

using u32 = unsigned int;
using f16x8 = __attribute__((ext_vector_type(8))) _Float16;
using f32x4 = __attribute__((ext_vector_type(4))) float;

__device__ __forceinline__ float sigmoidf_(float v) {
  return 1.f / (1.f + expf(-v));
}
__device__ __forceinline__ float ld2_(const float* p) { return *p; }
__device__ __forceinline__ float ld2_(const _Float16* p) { return (float)*p; }
__device__ __forceinline__ void st2_(float* p, float v) { *p = v; }
__device__ __forceinline__ void st2_(_Float16* p, float v) { *p = (_Float16)v; }
__device__ __forceinline__ f16x8 bc_(uint4 u) {
  union { uint4 u; f16x8 h; } x; x.u = u; return x.h;
}
__device__ __forceinline__ u32 pk_(float a, float b) {
  union { u32 u; _Float16 h[2]; } x; x.h[0] = (_Float16)a; x.h[1] = (_Float16)b;
  return x.u;
}

// ---- diagnostic fill ----
__global__ __launch_bounds__(256) void dsta_fill(float* __restrict__ out,
                                                 int n, float v) {
  int i = blockIdx.x * 256 + threadIdx.x;
  if (i < n) out[i] = v;
}

// ---- conv1: x(B,64,H,W) -> x2(B,32,H,W), 3x3 pad1, bias, relu ----
__global__ __launch_bounds__(256) void dsta_conv1(
    const float* __restrict__ x, const float* __restrict__ wgt,
    const float* __restrict__ bias, float* __restrict__ x2) {
  int idx = blockIdx.x * 256 + threadIdx.x;
  int p = idx % HW; int r = idx / HW;
  int g = r % 4, b = r / 4;
  int h = p / W, w = p % W;
  float acc[8];
#pragma unroll
  for (int j = 0; j < 8; ++j) acc[j] = bias[g * 8 + j];
  for (int ci = 0; ci < N; ++ci) {
    const float* xp = x + ((size_t)(b * N + ci)) * HW;
    float tap[9];
#pragma unroll
    for (int t = 0; t < 9; ++t) {
      int yy = h + t / 3 - 1, xx = w + t % 3 - 1;
      tap[t] = (yy >= 0 && yy < H && xx >= 0 && xx < W) ? xp[yy * W + xx] : 0.f;
    }
#pragma unroll
    for (int j = 0; j < 8; ++j) {
      const float* wp = wgt + ((size_t)(g * 8 + j) * N + ci) * 9;
#pragma unroll
      for (int t = 0; t < 9; ++t) acc[j] = fmaf(wp[t], tap[t], acc[j]);
    }
  }
#pragma unroll
  for (int j = 0; j < 8; ++j)
    x2[((size_t)(b * F + g * 8 + j)) * HW + p] = fmaxf(acc[j], 0.f);
}

// ---- channel mean & max maps -> stats(B,2,H,W) ----
__global__ __launch_bounds__(256) void dsta_stats(
    const float* __restrict__ x2, float* __restrict__ stats) {
  int idx = blockIdx.x * 256 + threadIdx.x;
  int p = idx % HW, b = idx / HW;
  float s = 0.f, m = -3.4e38f;
  for (int c = 0; c < F; ++c) {
    float v = x2[((size_t)(b * F + c)) * HW + p];
    s += v; m = fmaxf(m, v);
  }
  stats[((size_t)(b * 2 + 0)) * HW + p] = s * (1.f / F);
  stats[((size_t)(b * 2 + 1)) * HW + p] = m;
}

// ---- per-(b,c) spatial mean & max ----
__global__ __launch_bounds__(256) void dsta_ca_red(
    const float* __restrict__ x2, float* __restrict__ ap, float* __restrict__ mp) {
  __shared__ float ss[256], sm[256];
  int bc = blockIdx.x;
  const float* src = x2 + (size_t)bc * HW;
  float s = 0.f, m = -3.4e38f;
  for (int i = threadIdx.x; i < HW; i += 256) {
    float v = src[i]; s += v; m = fmaxf(m, v);
  }
  ss[threadIdx.x] = s; sm[threadIdx.x] = m;
  __syncthreads();
  for (int o = 128; o > 0; o >>= 1) {
    if (threadIdx.x < o) {
      ss[threadIdx.x] += ss[threadIdx.x + o];
      sm[threadIdx.x] = fmaxf(sm[threadIdx.x], sm[threadIdx.x + o]);
    }
    __syncthreads();
  }
  if (threadIdx.x == 0) { ap[bc] = ss[0] * (1.f / HW); mp[bc] = sm[0]; }
}

// ---- channel-attention MLP ----
__global__ __launch_bounds__(128) void dsta_ca_mlp(
    const float* __restrict__ ap, const float* __restrict__ mp,
    const float* __restrict__ w1, const float* __restrict__ w2,
    float* __restrict__ sig) {
  int t = threadIdx.x;
  if (t >= B * F) return;
  int b = t / F, co = t % F;
  float accA = 0.f, accB = 0.f;
  for (int j = 0; j < F / 2; ++j) {
    float hA = 0.f, hB = 0.f;
    for (int c = 0; c < F; ++c) {
      float wv = w1[j * F + c];
      hA = fmaf(wv, ap[b * F + c], hA);
      hB = fmaf(wv, mp[b * F + c], hB);
    }
    hA = fmaxf(hA, 0.f); hB = fmaxf(hB, 0.f);
    float wv2 = w2[co * (F / 2) + j];
    accA = fmaf(wv2, hA, accA);
    accB = fmaf(wv2, hB, accB);
  }
  sig[t] = sigmoidf_(accA + accB);
}

// ---- spatial attention: 7x7 conv(pad3), silu ----
__global__ __launch_bounds__(256) void dsta_sa(
    const float* __restrict__ stats, const float* __restrict__ wgt,
    float* __restrict__ x2s) {
  int idx = blockIdx.x * 256 + threadIdx.x;
  int p = idx % HW; int r = idx / HW;
  int g = r % 4, b = r / 4;
  int h = p / W, w = p % W;
  float acc[8];
#pragma unroll
  for (int j = 0; j < 8; ++j) acc[j] = 0.f;
  for (int ci = 0; ci < 2; ++ci) {
    const float* sp = stats + ((size_t)(b * 2 + ci)) * HW;
    for (int ky = 0; ky < 7; ++ky) {
      int yy = h + ky - 3;
      float tap[7];
#pragma unroll
      for (int kx = 0; kx < 7; ++kx) {
        int xx = w + kx - 3;
        tap[kx] = (yy >= 0 && yy < H && xx >= 0 && xx < W) ? sp[yy * W + xx] : 0.f;
      }
#pragma unroll
      for (int j = 0; j < 8; ++j) {
        const float* wp = wgt + (((size_t)(g * 8 + j) * 2 + ci) * 49) + ky * 7;
#pragma unroll
        for (int kx = 0; kx < 7; ++kx) acc[j] = fmaf(wp[kx], tap[kx], acc[j]);
      }
    }
  }
#pragma unroll
  for (int j = 0; j < 8; ++j) {
    float v = acc[j];
    x2s[((size_t)(b * F + g * 8 + j)) * HW + p] = sigmoidf_(v) * v;
  }
}

// ---- fuse ----
__global__ __launch_bounds__(256) void dsta_fuse(
    const float* __restrict__ x2s, const float* __restrict__ x2,
    const float* __restrict__ sig, const float* __restrict__ fw,
    const float* __restrict__ fb, float* __restrict__ x2f) {
  int idx = blockIdx.x * 256 + threadIdx.x;
  int p = idx % HW, b = idx / HW;
  float acc[F];
#pragma unroll
  for (int o = 0; o < F; ++o) acc[o] = fb[o];
  for (int c = 0; c < F; ++c) {
    float v = x2s[((size_t)(b * F + c)) * HW + p];
#pragma unroll
    for (int o = 0; o < F; ++o) acc[o] = fmaf(fw[o * 2 * F + c], v, acc[o]);
  }
  for (int c = 0; c < F; ++c) {
    float v = sig[b * F + c] * x2[((size_t)(b * F + c)) * HW + p];
#pragma unroll
    for (int o = 0; o < F; ++o) acc[o] = fmaf(fw[o * 2 * F + F + c], v, acc[o]);
  }
#pragma unroll
  for (int o = 0; o < F; ++o)
    x2f[((size_t)(b * F + o)) * HW + p] = fmaxf(acc[o], 0.f);
}

// ---- down: 3x3 s2 p1 conv 32->32 + relu ----
__global__ __launch_bounds__(256) void dsta_down(
    const float* __restrict__ x2f, const float* __restrict__ wgt,
    const float* __restrict__ bias, float* __restrict__ x3) {
  int idx = blockIdx.x * 256 + threadIdx.x;
  int p = idx % HW2; int r = idx / HW2;
  int g = r % 4, b = r / 4;
  int h2 = p / W2, w2 = p % W2;
  float acc[8];
#pragma unroll
  for (int j = 0; j < 8; ++j) acc[j] = bias[g * 8 + j];
  for (int ci = 0; ci < F; ++ci) {
    const float* xp = x2f + ((size_t)(b * F + ci)) * HW;
    float tap[9];
#pragma unroll
    for (int t = 0; t < 9; ++t) {
      int yy = 2 * h2 + t / 3 - 1, xx = 2 * w2 + t % 3 - 1;
      tap[t] = (yy >= 0 && yy < H && xx >= 0 && xx < W) ? xp[yy * W + xx] : 0.f;
    }
#pragma unroll
    for (int j = 0; j < 8; ++j) {
      const float* wp = wgt + ((size_t)(g * 8 + j) * F + ci) * 9;
#pragma unroll
      for (int t = 0; t < 9; ++t) acc[j] = fmaf(wp[t], tap[t], acc[j]);
    }
  }
#pragma unroll
  for (int j = 0; j < 8; ++j)
    x3[((size_t)(b * F + g * 8 + j)) * HW2 + p] = fmaxf(acc[j], 0.f);
}

// ---- weight frag-pack (fp16 pairs), same k-map as im2col builder ----
__global__ __launch_bounds__(256) void dsta_pack(
    const float* __restrict__ mw, const float* __restrict__ m2w,
    u32* __restrict__ pw1, u32* __restrict__ pw2) {
  int i = blockIdx.x * 256 + threadIdx.x;   // 271,872 total
  if (i < 147456) {
    int r = i & 3, l = (i >> 2) & 63;
    int kt = (i >> 8) % 9, q = (i >> 8) / 9;
    int mt = q & 1, c = q >> 1;
    int ochl = mt * 16 + (l & 15);
    int k0 = kt * 32 + 8 * (l >> 4) + 2 * r;
    float v0 = 0.f, v1 = 0.f;
    if (ochl < 27) {
      int ochg = ochl < 18 ? c * 18 + ochl : 576 + c * 9 + (ochl - 18);
      v0 = mw[(size_t)ochg * 288 + k0];
      v1 = mw[(size_t)ochg * 288 + k0 + 1];
    }
    pw1[i] = pk_(v0, v1);
  } else {
    int i2 = i - 147456;                    // 124,416
    int r = i2 & 3, l = (i2 >> 2) & 63;
    int kt = (i2 >> 8) % 9, mt = (i2 >> 8) / 9;
    int och = mt * 16 + (l & 15);
    int k0 = kt * 32 + 8 * (l >> 4) + 2 * r;
    pw2[i2] = pk_(m2w[(size_t)och * 288 + k0], m2w[(size_t)och * 288 + k0 + 1]);
  }
}

// ---- cooperative im2col builder: 8x8 px tile -> fp16 frags in LDS ----
template <int SH, int SW>
__device__ __forceinline__ void build_im2col(
    const float* __restrict__ src, int y0t, int x0t,
    float* __restrict__ patch, u32* __restrict__ im2, int tid) {
  for (int i = tid; i < F * 100; i += 256) {
    int ci = i / 100, rr = i % 100;
    int yy = y0t + rr / 10 - 1, xx = x0t + rr % 10 - 1;
    patch[i] = (yy >= 0 && yy < SH && xx >= 0 && xx < SW)
                   ? src[(size_t)ci * (SH * SW) + yy * SW + xx] : 0.f;
  }
  __syncthreads();
  for (int i = tid; i < 9216; i += 256) {
    int r = i & 3, l = (i >> 2) & 63;
    int kt = (i >> 8) % 9, nt = (i >> 8) / 9;
    int j = nt * 16 + (l & 15);
    int ly = j >> 3, lx = j & 7;
    int k0 = kt * 32 + 8 * (l >> 4) + 2 * r;
    int ci0 = k0 / 9, t0 = k0 - 9 * ci0;
    int k1 = k0 + 1;
    int ci1 = k1 / 9, t1 = k1 - 9 * ci1;
    float v0 = patch[ci0 * 100 + (ly + t0 / 3) * 10 + (lx + t0 % 3)];
    float v1 = patch[ci1 * 100 + (ly + t1 / 3) * 10 + (lx + t1 % 3)];
    im2[i] = pk_(v0, v1);
  }
  __syncthreads();
}

// ---- om2 via MFMA: 3x3 p1 conv 32->864 over x3, + mask2_b ----
// grid = B * 144 tiles * 2 chunks (cs); wave w handles mt = cs*27+w .. +27.
template <typename T>
__global__ __launch_bounds__(256) void dsta_om2_m(
    const float* __restrict__ x3, const uint4* __restrict__ pw2,
    const float* __restrict__ bias, T* __restrict__ om2) {
  __shared__ float s_patch[F * 100];
  __shared__ uint4 s_col[2304];
  int bid = blockIdx.x;                 // B*144*2
  int cs = bid & 1;
  int tile = (bid >> 1) % 144, b = bid / 288;
  int y0t = (tile / 12) * 8, x0t = (tile % 12) * 8;
  int tid = threadIdx.x;
  build_im2col<H2, W2>(x3 + (size_t)b * F * HW2, y0t, x0t, s_patch,
                       (u32*)s_col, tid);
  int w = tid >> 6, l = tid & 63;
  int lg = l >> 4, li = l & 15;
  for (int mt = cs * 27 + w; mt < cs * 27 + 27; mt += 4) {
    uint4 wf[9];
#pragma unroll
    for (int kt = 0; kt < 9; ++kt) wf[kt] = pw2[(mt * 9 + kt) * 64 + l];
    float b4[4];
#pragma unroll
    for (int rg = 0; rg < 4; ++rg) b4[rg] = bias[mt * 16 + lg * 4 + rg];
#pragma unroll
    for (int nt = 0; nt < 4; ++nt) {
      f32x4 acc = {0.f, 0.f, 0.f, 0.f};
#pragma unroll
      for (int kt = 0; kt < 9; ++kt)
        acc = __builtin_amdgcn_mfma_f32_16x16x32_f16(
            bc_(wf[kt]), bc_(s_col[(nt * 9 + kt) * 64 + l]), acc, 0, 0, 0);
      int j = nt * 16 + li;
      int gy = y0t + (j >> 3), gx = x0t + (j & 7);
#pragma unroll
      for (int rg = 0; rg < 4; ++rg) {
        int och = mt * 16 + lg * 4 + rg;
        st2_(&om2[((size_t)(b * OMC + och)) * HW2 + gy * W2 + gx],
             acc[rg] + b4[rg]);
      }
    }
  }
}

// ---- dcn via MFMA: per-tile om1 GEMM + bilinear om2 + DCNv2 sampling ----
// 256 thr = 4 waves; wave w owns c in [w*8, w*8+8); per-lane pixel = lane.
// NOTE: no min-occupancy pledge — R5's (256,2) capped VGPRs at 128 and the
// compiler spilled ~4 GB of scratch per dispatch. LDS (69.6 KB) caps
// residency at 2 blocks/CU regardless.
template <typename T>
__global__ __launch_bounds__(256) void dsta_dcn_m(
    const float* __restrict__ x2f, const T* __restrict__ om2,
    const uint4* __restrict__ pw1, const float* __restrict__ mb,
    const float* __restrict__ dw, const float* __restrict__ db,
    float* __restrict__ dcn) {
  __shared__ uint4 s_col[2304];          // 36,864 B; later aliased as s_red
  __shared__ float s_om[4 * 32 * 64];    // 32,768 B; first 3200 = patch
  int bid = blockIdx.x;                  // B*576
  int tile = bid % 576, b = bid / 576;
  int y0t = (tile / 24) * 8, x0t = (tile % 24) * 8;
  int tid = threadIdx.x;
  const float* xb = x2f + (size_t)b * F * HW;
  build_im2col<H, W>(xb, y0t, x0t, s_om, (u32*)s_col, tid);

  int w = tid >> 6, l = tid & 63;
  int lg = l >> 4, li = l & 15;
  int hq = y0t + (l >> 3), wq = x0t + (l & 7);

  // bilinear setup (jax resize: src = dst*0.5 - 0.25, clamped taps)
  float sy = hq * 0.5f - 0.25f, sx = wq * 0.5f - 0.25f;
  float fy0 = floorf(sy), fx0 = floorf(sx);
  float gy = sy - fy0, gx = sx - fx0;
  int y0 = (int)fy0, x0 = (int)fx0;
  int y0c = min(max(y0, 0), H2 - 1), y1c = min(max(y0 + 1, 0), H2 - 1);
  int x0c = min(max(x0, 0), W2 - 1), x1c = min(max(x0 + 1, 0), W2 - 1);
  float b00 = (1.f - gy) * (1.f - gx), b01 = (1.f - gy) * gx;
  float b10 = gy * (1.f - gx), b11 = gy * gx;
  int i00 = y0c * W2 + x0c, i01 = y0c * W2 + x1c;
  int i10 = y1c * W2 + x0c, i11 = y1c * W2 + x1c;
  const T* om2b = om2 + (size_t)b * OMC * HW2;

  float accd[F];
#pragma unroll
  for (int o = 0; o < F; ++o) accd[o] = 0.f;
  float* s_omw = s_om + w * (32 * 64);

  for (int cc = 0; cc < 8; ++cc) {
    int c = w * 8 + cc;
    // (a) om1 quadrants via MFMA -> wave-private LDS slab (accd + acc live)
#pragma unroll
    for (int mt = 0; mt < 2; ++mt) {
      uint4 wf[9];
#pragma unroll
      for (int kt = 0; kt < 9; ++kt)
        wf[kt] = pw1[(((c * 2 + mt) * 9) + kt) * 64 + l];
#pragma unroll
      for (int nt = 0; nt < 4; ++nt) {
        f32x4 acc = {0.f, 0.f, 0.f, 0.f};
#pragma unroll
        for (int kt = 0; kt < 9; ++kt)
          acc = __builtin_amdgcn_mfma_f32_16x16x32_f16(
              bc_(wf[kt]), bc_(s_col[(nt * 9 + kt) * 64 + l]), acc, 0, 0, 0);
        int j = nt * 16 + li;
#pragma unroll
        for (int rg = 0; rg < 4; ++rg) {
          int ch = mt * 16 + lg * 4 + rg;
          if (ch < 27) s_omw[ch * 64 + j] = acc[rg];
        }
      }
    }
    // (b) bilinear om2 + mask1_b (omv becomes live only after MFMA block)
    float omv[27];
#pragma unroll
    for (int j = 0; j < 27; ++j) {
      int ch = (j < 18) ? (c * 18 + j) : (576 + c * 9 + (j - 18));
      const T* pl = om2b + (size_t)ch * HW2;
      omv[j] = mb[ch] + b00 * ld2_(pl + i00) + b01 * ld2_(pl + i01) +
               b10 * ld2_(pl + i10) + b11 * ld2_(pl + i11);
    }
    // (c) assemble om (intra-wave LDS dep; compiler emits lgkmcnt wait)
#pragma unroll
    for (int j = 0; j < 27; ++j) omv[j] += s_omw[j * 64 + l];
    // (d) deformable sampling + dcn partial einsum
    const float* xc = xb + (size_t)c * HW;
#pragma unroll
    for (int k = 0; k < 9; ++k) {
      float m = sigmoidf_(omv[18 + k]);
      float py = (float)(hq + k / 3 - 1) + omv[2 * k];
      float px = (float)(wq + k % 3 - 1) + omv[2 * k + 1];
      float fpy = floorf(py), fpx = floorf(px);
      int yi = (int)fpy, xi = (int)fpx;
      float wy = py - fpy, wx = px - fpx;
      float v00 = (yi >= 0 && yi < H && xi >= 0 && xi < W) ? xc[yi * W + xi] : 0.f;
      float v01 = (yi >= 0 && yi < H && xi + 1 >= 0 && xi + 1 < W) ? xc[yi * W + xi + 1] : 0.f;
      float v10 = (yi + 1 >= 0 && yi + 1 < H && xi >= 0 && xi < W) ? xc[(yi + 1) * W + xi] : 0.f;
      float v11 = (yi + 1 >= 0 && yi + 1 < H && xi + 1 >= 0 && xi + 1 < W) ? xc[(yi + 1) * W + xi + 1] : 0.f;
      float val = (v00 * (1.f - wy) * (1.f - wx) + v01 * (1.f - wy) * wx +
                   v10 * wy * (1.f - wx) + v11 * wy * wx) * m;
#pragma unroll
      for (int o = 0; o < F; ++o)
        accd[o] = fmaf(val, dw[(o * F + c) * 9 + k], accd[o]);
    }
  }
  // cross-wave reduction (stride 33 -> conflict-free)
  __syncthreads();
  float* s_red = (float*)s_col;
#pragma unroll
  for (int o = 0; o < F; ++o) s_red[(w * 64 + l) * 33 + o] = accd[o];
  __syncthreads();
  int px_ = tid & 63, og = tid >> 6;
  int hp = y0t + (px_ >> 3), wp = x0t + (px_ & 7);
#pragma unroll
  for (int oo = 0; oo < 8; ++oo) {
    int o = og * 8 + oo;
    float s = db[o];
#pragma unroll
    for (int w2 = 0; w2 < 4; ++w2) s += s_red[(w2 * 64 + px_) * 33 + o];
    dcn[((size_t)(b * F + o)) * HW + hp * W + wp] = fmaxf(s, 0.f);
  }
}

// ---- out: 3x3 p1 conv 32->64 + bias + relu, FP32 output ----
__global__ __launch_bounds__(256) void dsta_out(
    const float* __restrict__ dcn, const float* __restrict__ wgt,
    const float* __restrict__ bias, float* __restrict__ out) {
  int idx = blockIdx.x * 256 + threadIdx.x;
  int p = idx % HW; int r = idx / HW;
  int g = r % 8, b = r / 8;
  int h = p / W, w = p % W;
  float acc[8];
#pragma unroll
  for (int j = 0; j < 8; ++j) acc[j] = bias[g * 8 + j];
  for (int ci = 0; ci < F; ++ci) {
    const float* xp = dcn + ((size_t)(b * F + ci)) * HW;
    float tap[9];
#pragma unroll
    for (int t = 0; t < 9; ++t) {
      int yy = h + t / 3 - 1, xx = w + t % 3 - 1;
      tap[t] = (yy >= 0 && yy < H && xx >= 0 && xx < W) ? xp[yy * W + xx] : 0.f;
    }
#pragma unroll
    for (int j = 0; j < 8; ++j) {
      const float* wp = wgt + ((size_t)(g * 8 + j) * F + ci) * 9;
#pragma unroll
      for (int t = 0; t < 9; ++t) acc[j] = fmaf(wp[t], tap[t], acc[j]);
    }
  }
#pragma unroll
  for (int j = 0; j < 8; ++j)
    out[((size_t)(b * N + g * 8 + j)) * HW + p] = fmaxf(acc[j], 0.f);
}

extern "C" void kernel_launch(void* const* d_in, const int* in_sizes, int n_in,
                              void* d_out, int out_size, void* d_ws, size_t ws_size,
                              hipStream_t stream) {
  float* out = (float*)d_out;
  const int fill_grid = (out_size + 255) / 256;

  static const int idmap[18]  = {0,1,2,3,4,5,6,7,8,9,10,11,12,13,14,15,16,17};
  static const int alphamap[18] = {17,3,2,16,0,1,9,8,11,10,7,6,13,12,5,4,15,14};
  const int* map = nullptr;
  if (n_in == 18 && in_sizes[0] == 9437184) map = idmap;
  else if (n_in == 18 && in_sizes[17] == 9437184) map = alphamap;
  if (!map) {
    dsta_fill<<<fill_grid, 256, 0, stream>>>(out, out_size, 2.0e6f);
    return;
  }
  if (in_sizes[map[8]] != 248832 || in_sizes[map[16]] != 18432) {
    dsta_fill<<<fill_grid, 256, 0, stream>>>(out, out_size, 3.0e6f);
    return;
  }

  const float* x       = (const float*)d_in[map[0]];
  const float* conv1_w = (const float*)d_in[map[1]];
  const float* conv1_b = (const float*)d_in[map[2]];
  const float* sa_w    = (const float*)d_in[map[3]];
  const float* ca_w1   = (const float*)d_in[map[4]];
  const float* ca_w2   = (const float*)d_in[map[5]];
  const float* fuse_w  = (const float*)d_in[map[6]];
  const float* fuse_b  = (const float*)d_in[map[7]];
  const float* mask1_w = (const float*)d_in[map[8]];
  const float* mask1_b = (const float*)d_in[map[9]];
  const float* down_w  = (const float*)d_in[map[10]];
  const float* down_b  = (const float*)d_in[map[11]];
  const float* mask2_w = (const float*)d_in[map[12]];
  const float* mask2_b = (const float*)d_in[map[13]];
  const float* dcn_w   = (const float*)d_in[map[14]];
  const float* dcn_b   = (const float*)d_in[map[15]];
  const float* out_w   = (const float*)d_in[map[16]];
  const float* out_b   = (const float*)d_in[map[17]];

  float* ws = (float*)d_ws;
  float* x2    = ws;                                 // 4,718,592 f32
  float* x2s   = x2  + (size_t)B * F * HW;
  float* x2f   = x2s + (size_t)B * F * HW;
  float* x3    = x2f + (size_t)B * F * HW;
  float* stats = x3  + (size_t)B * F * HW2;
  float* ap    = stats + (size_t)B * 2 * HW;
  float* mp    = ap + B * F;
  float* sig   = mp + B * F;
  float* om2f  = sig + B * F;                        // 31,850,496 elems
  float* dcn   = x2;  // alias: x2 dead after dsta_fuse

  // frag-packed weights live in d_out scratch; overwritten by dsta_out.
  u32* pw1 = (u32*)d_out;              // 147,456 u32
  u32* pw2 = pw1 + 147456;             // 124,416 u32

  const size_t base_f32 = 15630720;
  const size_t need_f32 = (base_f32 + 31850496ull) * 4ull;          // ~181 MiB
  const size_t need_f16 = base_f32 * 4ull + 31850496ull * 2ull;     // ~120 MiB
  int om2_mode;
  if (ws_size >= need_f32) om2_mode = 0;
  else if (ws_size >= need_f16) om2_mode = 1;
  else {
    dsta_fill<<<fill_grid, 256, 0, stream>>>(
        out, out_size, 1.0e6f + (float)(ws_size >> 20));
    return;
  }

  dsta_conv1<<<2304, 256, 0, stream>>>(x, conv1_w, conv1_b, x2);
  dsta_stats<<<576, 256, 0, stream>>>(x2, stats);
  dsta_ca_red<<<128, 256, 0, stream>>>(x2, ap, mp);
  dsta_ca_mlp<<<1, 128, 0, stream>>>(ap, mp, ca_w1, ca_w2, sig);
  dsta_sa<<<2304, 256, 0, stream>>>(stats, sa_w, x2s);
  dsta_fuse<<<576, 256, 0, stream>>>(x2s, x2, sig, fuse_w, fuse_b, x2f);
  dsta_down<<<576, 256, 0, stream>>>(x2f, down_w, down_b, x3);
  dsta_pack<<<1062, 256, 0, stream>>>(mask1_w, mask2_w, pw1, pw2);
  if (om2_mode == 0) {
    dsta_om2_m<float><<<1152, 256, 0, stream>>>(x3, (const uint4*)pw2,
                                                mask2_b, om2f);
    dsta_dcn_m<float><<<2304, 256, 0, stream>>>(x2f, om2f, (const uint4*)pw1,
                                                mask1_b, dcn_w, dcn_b, dcn);
  } else {
    _Float16* om2h = (_Float16*)om2f;
    dsta_om2_m<_Float16><<<1152, 256, 0, stream>>>(x3, (const uint4*)pw2,
                                                   mask2_b, om2h);
    dsta_dcn_m<_Float16><<<2304, 256, 0, stream>>>(x2f, om2h, (const uint4*)pw1,
                                                   mask1_b, dcn_w, dcn_b, dcn);
  }
  dsta_out<<<4608, 256, 0, stream>>>(dcn, out_w, out_b, out);
}